// Round 1
// baseline (375.861 us; speedup 1.0000x reference)
//
#include <hip/hip_runtime.h>

#define B_SZ 2048
#define D_IN 256
#define L_N 48
#define H_N 256
#define O_N 10
#define WROW 303      // D + L - 1
#define LEAF_N 12336  // L*(D+1)
#define KC 2304       // L*L
#define KHAT 2352     // KC + L

// ---------------------------------------------------------------------------
// Kernel 1: Ghat[h, i*48+k] = sum_d W[k,d] * Wb0[h, i*257+d]   (i,k < 48)
//           Ghat[h, 2304+i] = Wb0[h, i*257+256]                (offset col)
// grid (48, 8), 256 threads. LDS: Wx (48x256) + Wb0 tile (32x256).
// ---------------------------------------------------------------------------
__global__ __launch_bounds__(256) void k_ghat(const float* __restrict__ W,
                                              const float* __restrict__ Wb0,
                                              float* __restrict__ Ghat) {
  const int i  = blockIdx.x;       // layer
  const int h0 = blockIdx.y * 32;  // h tile
  __shared__ float WxL[48][257];
  __shared__ float AL[32][257];
  const int t = threadIdx.x;
  for (int e = t; e < 48 * 256; e += 256) {
    int r = e >> 8, d = e & 255;
    WxL[r][d] = W[r * WROW + d];
  }
  for (int e = t; e < 32 * 256; e += 256) {
    int r = e >> 8, d = e & 255;
    AL[r][d] = Wb0[(size_t)(h0 + r) * LEAF_N + i * 257 + d];
  }
  __syncthreads();
  const int hl = t & 31;   // local h
  const int kg = t >> 5;   // k group 0..7 (6 k's each)
  float acc[6] = {0.f, 0.f, 0.f, 0.f, 0.f, 0.f};
  for (int d = 0; d < 256; ++d) {
    float a = AL[hl][d];
#pragma unroll
    for (int kk = 0; kk < 6; ++kk) acc[kk] += a * WxL[kg * 6 + kk][d];
  }
  float* grow = Ghat + (size_t)(h0 + hl) * KHAT + i * 48 + kg * 6;
#pragma unroll
  for (int kk = 0; kk < 6; ++kk) grow[kk] = acc[kk];
  if (t < 32)
    Ghat[(size_t)(h0 + t) * KHAT + KC + i] =
        Wb0[(size_t)(h0 + t) * LEAF_N + i * 257 + 256];
}

// ---------------------------------------------------------------------------
// Kernel 2: P[b,i] = dot(x[b,:], W[i,0:256])    (2048 x 48, K=256)
// one thread per (b,i); grid 384 x 256 threads.
// ---------------------------------------------------------------------------
__global__ __launch_bounds__(256) void k_p(const float* __restrict__ x,
                                           const float* __restrict__ W,
                                           float* __restrict__ P) {
  int idx = blockIdx.x * 256 + threadIdx.x;  // 0..98303
  int b = idx / 48, i = idx - b * 48;
  const float* xr = x + (size_t)b * D_IN;
  const float* wr = W + (size_t)i * WROW;
  float acc = 0.f;
  for (int d = 0; d < 256; ++d) acc += xr[d] * wr[d];
  P[idx] = acc;
}

// ---------------------------------------------------------------------------
// Kernel 3: per-batch sequential part. 1 wave (64 thr) per batch row.
//  phase 1: z recurrence (butterfly reduce), masks, a, d
//  phase 2: S = (I-T)^-1 forward substitution, lane j owns column j in LDS
//  phase 3: offs_i = a_i - d_i * sum_k S[i,k] P[b,k]
//  phase 4: Chat[b] = [d_i * S[i,k] | offs], masks -> d_out
// ---------------------------------------------------------------------------
__global__ __launch_bounds__(64) void k_seq(const float* __restrict__ W,
                                            const float* __restrict__ bvec,
                                            const float* __restrict__ P,
                                            float* __restrict__ Chat,
                                            float* __restrict__ mask_out) {
  const int b = blockIdx.x;
  const int lane = threadIdx.x;
  __shared__ float whL[48][48];  // whL[i][k] = W[i, 256+k]
  __shared__ float S[48][64];    // lower-tri, cols 48..63 scratch-zero
  __shared__ float aL[48];
  __shared__ float offsL[48];

  // phase 0: stage wh, zero S
  for (int e = lane; e < 48 * 48; e += 64) {
    int i = e / 48, k = e - i * 48;
    whL[i][k] = (k < 47) ? W[i * WROW + 256 + k] : 0.f;  // row len 303
  }
  for (int e = lane; e < 48 * 64; e += 64) ((float*)S)[e] = 0.f;
  __syncthreads();
  if (lane < 48) S[lane][lane] = 1.f;  // diag (own column)

  float Preg = (lane < 48) ? P[b * 48 + lane] : 0.f;
  float breg = (lane < 48) ? bvec[lane] : 0.f;
  float a_lane = 0.f;
  int d_lane = 0;

  // phase 1: z_i = P[b,i] + b_i + sum_{k<i} wh_i[k] * a_k
  for (int i = 0; i < 48; ++i) {
    float term = (lane < i) ? whL[i][lane] * a_lane : 0.f;
#pragma unroll
    for (int m = 32; m >= 1; m >>= 1) term += __shfl_xor(term, m);
    float z = __shfl(Preg, i) + __shfl(breg, i) + term;
    float ai = fmaxf(z, 0.f);
    if (lane == i) {
      a_lane = ai;
      d_lane = (z > 0.f) ? 1 : 0;
      aL[i] = ai;
    }
  }
  unsigned long long dmask = __ballot(d_lane != 0);

  // phase 2: S[i][j] = sum_{k=j..i-1} (wh_i[k]*d_k) * S[k][j]  (lane j = col j)
  for (int i = 1; i < 48; ++i) {
    float sum = 0.f;
    for (int k = 0; k < i; ++k) {
      float t_ik = ((dmask >> k) & 1ULL) ? whL[i][k] : 0.f;  // broadcast
      sum += t_ik * S[k][lane];  // own-column read (written by this lane)
    }
    if (lane < i) S[i][lane] = sum;
  }
  __syncthreads();  // aL + S visible to all lanes

  // phase 3: offs_i = a_i - d_i * sum_k S[i][k] * P[b,k]
  for (int i = 0; i < 48; ++i) {
    float term = S[i][lane] * Preg;  // cols>=48 are 0, Preg 0 there too
#pragma unroll
    for (int m = 32; m >= 1; m >>= 1) term += __shfl_xor(term, m);
    if (lane == i) {
      float d = ((dmask >> (unsigned)i) & 1ULL) ? 1.f : 0.f;
      offsL[i] = aL[i] - d * term;
    }
  }
  __syncthreads();

  // phase 4: write Chat row + masks
  float* crow = Chat + (size_t)b * KHAT;
  for (int e = lane; e < KC; e += 64) {
    int i = e / 48, k = e - i * 48;
    float d = ((dmask >> (unsigned)i) & 1ULL) ? 1.f : 0.f;
    crow[e] = d * S[i][k];
  }
  if (lane < 48) {
    crow[KC + lane] = offsL[lane];
    mask_out[b * 48 + lane] = ((dmask >> (unsigned)lane) & 1ULL) ? 1.f : 0.f;
  }
}

// ---------------------------------------------------------------------------
// Tiled fp32 NT GEMM: out[m,n] = sum_k A[m,k]*B[n,k]  (+bias, relu if FINAL)
// BM=BN=64, TM=TN=4, 256 threads (tn = t&15 fast for coalesced stores).
// K-split via blockIdx.z -> separate partial buffers (deterministic).
// ---------------------------------------------------------------------------
template <int BK, bool FINAL>
__global__ __launch_bounds__(256) void k_gemm_nt(const float* __restrict__ A,
                                                 const float* __restrict__ Bm,
                                                 const float* __restrict__ bias,
                                                 float* __restrict__ Cdst,
                                                 int K, int CHUNK) {
  const int m0 = blockIdx.x * 64;
  const int n0 = blockIdx.y * 64;
  const int k0 = blockIdx.z * CHUNK;
  float* dst = Cdst + (size_t)blockIdx.z * (size_t)B_SZ * H_N;
  __shared__ float At[BK][68];
  __shared__ float Bt[BK][68];
  const int t = threadIdx.x;
  const int tn = t & 15, tm = t >> 4;
  float acc[4][4] = {};
  const int iters = CHUNK / BK;
  for (int it = 0; it < iters; ++it) {
    int kb = k0 + it * BK;
    for (int e = t; e < 64 * BK; e += 256) {
      int m = e / BK, k = e - m * BK;
      At[k][m] = A[(size_t)(m0 + m) * K + kb + k];
    }
    for (int e = t; e < 64 * BK; e += 256) {
      int n = e / BK, k = e - n * BK;
      Bt[k][n] = Bm[(size_t)(n0 + n) * K + kb + k];
    }
    __syncthreads();
#pragma unroll
    for (int k = 0; k < BK; ++k) {
      float4 av = *(const float4*)&At[k][tm * 4];
      float4 bv = *(const float4*)&Bt[k][tn * 4];
      float aa[4] = {av.x, av.y, av.z, av.w};
      float bb[4] = {bv.x, bv.y, bv.z, bv.w};
#pragma unroll
      for (int ii = 0; ii < 4; ++ii)
#pragma unroll
        for (int jj = 0; jj < 4; ++jj) acc[ii][jj] += aa[ii] * bb[jj];
    }
    __syncthreads();
  }
#pragma unroll
  for (int ii = 0; ii < 4; ++ii) {
    int m = m0 + tm * 4 + ii;
    float* o = dst + (size_t)m * H_N + n0 + tn * 4;
    float4 v;
    if constexpr (FINAL) {
      v.x = fmaxf(acc[ii][0] + bias[n0 + tn * 4 + 0], 0.f);
      v.y = fmaxf(acc[ii][1] + bias[n0 + tn * 4 + 1], 0.f);
      v.z = fmaxf(acc[ii][2] + bias[n0 + tn * 4 + 2], 0.f);
      v.w = fmaxf(acc[ii][3] + bias[n0 + tn * 4 + 3], 0.f);
    } else {
      v = make_float4(acc[ii][0], acc[ii][1], acc[ii][2], acc[ii][3]);
    }
    *(float4*)o = v;
  }
}

// ---------------------------------------------------------------------------
// h0 = relu(part0+part1+part2+part3 + bb0)   (float4, grid 512 x 256)
// ---------------------------------------------------------------------------
__global__ __launch_bounds__(256) void k_reduce_relu(const float* __restrict__ part,
                                                     const float* __restrict__ bias,
                                                     float* __restrict__ h0) {
  int idx = blockIdx.x * 256 + threadIdx.x;  // float4 index, 131072 total
  const float4* p = (const float4*)part;
  float4 a = p[idx];
  float4 b4 = p[idx + 131072];
  float4 c = p[idx + 262144];
  float4 d = p[idx + 393216];
  int n0 = (idx * 4) & 255;
  float4 bi = *(const float4*)&bias[n0];
  float4 r;
  r.x = fmaxf(a.x + b4.x + c.x + d.x + bi.x, 0.f);
  r.y = fmaxf(a.y + b4.y + c.y + d.y + bi.y, 0.f);
  r.z = fmaxf(a.z + b4.z + c.z + d.z + bi.z, 0.f);
  r.w = fmaxf(a.w + b4.w + c.w + d.w + bi.w, 0.f);
  ((float4*)h0)[idx] = r;
}

// ---------------------------------------------------------------------------
// out[b,o] = sum_k h1[b,k]*Wout[o,k] + bout[o]   (one thread per batch)
// ---------------------------------------------------------------------------
__global__ __launch_bounds__(256) void k_out(const float* __restrict__ h1,
                                             const float* __restrict__ Wout,
                                             const float* __restrict__ bout,
                                             float* __restrict__ out) {
  __shared__ float WL[10][256];
  int t = threadIdx.x;
  for (int e = t; e < 10 * 256; e += 256) WL[e >> 8][e & 255] = Wout[e];
  __syncthreads();
  int b = blockIdx.x * 256 + t;
  const float* hr = h1 + (size_t)b * 256;
  float acc[10] = {};
  for (int k = 0; k < 256; ++k) {
    float h = hr[k];
#pragma unroll
    for (int o = 0; o < 10; ++o) acc[o] += h * WL[o][k];
  }
#pragma unroll
  for (int o = 0; o < 10; ++o) out[b * 10 + o] = acc[o] + bout[o];
}

// ---------------------------------------------------------------------------
extern "C" void kernel_launch(void* const* d_in, const int* in_sizes, int n_in,
                              void* d_out, int out_size, void* d_ws,
                              size_t ws_size, hipStream_t stream) {
  (void)in_sizes; (void)n_in; (void)out_size; (void)ws_size;
  const float* x    = (const float*)d_in[0];
  const float* W    = (const float*)d_in[1];
  const float* bvec = (const float*)d_in[2];
  const float* Wb0  = (const float*)d_in[3];
  const float* bb0  = (const float*)d_in[4];
  const float* Wb1  = (const float*)d_in[5];
  const float* bb1  = (const float*)d_in[6];
  const float* Wout = (const float*)d_in[7];
  const float* bout = (const float*)d_in[8];

  float* out   = (float*)d_out;               // B*10 floats
  float* masks = out + B_SZ * O_N;            // B*48 floats (0/1)

  float* ws   = (float*)d_ws;
  float* P    = ws;                                   // 2048*48
  float* Chat = P + B_SZ * L_N;                       // 2048*2352
  float* Ghat = Chat + (size_t)B_SZ * KHAT;           // 256*2352
  float* part = Ghat + (size_t)H_N * KHAT;            // 4 * 2048*256
  float* h0   = part + 4 * (size_t)B_SZ * H_N;        // 2048*256
  float* h1   = h0 + (size_t)B_SZ * H_N;              // 2048*256
  // total ~32.5 MB of workspace

  k_ghat<<<dim3(48, 8), 256, 0, stream>>>(W, Wb0, Ghat);
  k_p<<<dim3(384), 256, 0, stream>>>(x, W, P);
  k_seq<<<dim3(2048), 64, 0, stream>>>(W, bvec, P, Chat, masks);
  // h0_pre = Chat @ Ghat^T, K=2352 split into 4 chunks of 588 (49 x BK=12)
  k_gemm_nt<12, false><<<dim3(32, 4, 4), 256, 0, stream>>>(Chat, Ghat, nullptr,
                                                           part, KHAT, 588);
  k_reduce_relu<<<dim3(512), 256, 0, stream>>>(part, bb0, h0);
  // h1 = relu(h0 @ Wb1^T + bb1), K=256 single chunk
  k_gemm_nt<32, true><<<dim3(32, 4, 1), 256, 0, stream>>>(h0, Wb1, bb1, h1,
                                                          256, 256);
  k_out<<<dim3(8), 256, 0, stream>>>(h1, Wout, bout, out);
}

// Round 3
// 185.613 us; speedup vs baseline: 2.0250x; 2.0250x over previous
//
#include <hip/hip_runtime.h>

#define B_SZ 2048
#define D_IN 256
#define L_N 48
#define H_N 256
#define O_N 10
#define WROW 303      // D + L - 1
#define LEAF_N 12336  // L*(D+1)
#define KC 2304       // L*L
#define KHAT 2352     // KC + L (valid cols)
#define KPAD 2560     // padded K for BK=32 GEMM

// ---------------------------------------------------------------------------
// Kernel 1: Ghat[h, k*48+i] = sum_d W[k,d] * Wb0[h, i*257+d]   (i,k < 48)
//           Ghat[h, 2304+i] = Wb0[h, i*257+256]                (offset col)
//           Ghat[h, 2352..2560) = 0                            (pad)
// grid (48 i, 4 h-tiles), 256 threads. Wave w handles k = w*12..w*12+11
// (wave-uniform -> W reads become scalar loads). LDS: Wb0 chunk 64h x 64d.
// ---------------------------------------------------------------------------
__global__ __launch_bounds__(256) void k_ghat(const float* __restrict__ W,
                                              const float* __restrict__ Wb0,
                                              float* __restrict__ Ghat) {
  const int i  = blockIdx.x;       // layer
  const int h0 = blockIdx.y * 64;  // h tile
  __shared__ float AT[64][69];     // [h][d] chunk, 69 stride: 2-way banks max
  const int t = threadIdx.x;
  const int lane = t & 63;
  const int wid = __builtin_amdgcn_readfirstlane(t >> 6);  // 0..3 (SGPR)
  float acc[12] = {};
  for (int dc = 0; dc < 256; dc += 64) {
    // stage Wb0[h0+r, i*257+dc+c], 4096 floats, scalar (row base misaligned)
    for (int e = t; e < 64 * 64; e += 256) {
      int r = e >> 6, c = e & 63;
      AT[r][c] = Wb0[(size_t)(h0 + r) * LEAF_N + i * 257 + dc + c];
    }
    __syncthreads();
#pragma unroll 4
    for (int d = 0; d < 64; ++d) {
      float a = AT[lane][d];
#pragma unroll
      for (int kk = 0; kk < 12; ++kk)
        acc[kk] += a * W[(wid * 12 + kk) * WROW + dc + d];  // scalar operand
    }
    __syncthreads();
  }
#pragma unroll
  for (int kk = 0; kk < 12; ++kk)
    Ghat[(size_t)(h0 + lane) * KPAD + (wid * 12 + kk) * 48 + i] = acc[kk];
  if (wid == 0)
    Ghat[(size_t)(h0 + lane) * KPAD + KC + i] =
        Wb0[(size_t)(h0 + lane) * LEAF_N + i * 257 + 256];
  if (i == 0) {  // pad-zero [2352,2560) for this h tile
    for (int e = t; e < 64 * 52; e += 256) {
      int r = e / 52, c = e - r * 52;
      *(float4*)&Ghat[(size_t)(h0 + r) * KPAD + KHAT + c * 4] =
          make_float4(0.f, 0.f, 0.f, 0.f);
    }
  }
}

// ---------------------------------------------------------------------------
// Kernel 2: P[b,i] = dot(x[b,:], W[i,0:256])
// ---------------------------------------------------------------------------
__global__ __launch_bounds__(256) void k_p(const float* __restrict__ x,
                                           const float* __restrict__ W,
                                           float* __restrict__ P) {
  int idx = blockIdx.x * 256 + threadIdx.x;  // 0..98303
  int b = idx / 48, i = idx - b * 48;
  const float* xr = x + (size_t)b * D_IN;
  const float* wr = W + (size_t)i * WROW;
  float acc = 0.f;
#pragma unroll 4
  for (int d = 0; d < 256; ++d) acc += xr[d] * wr[d];
  P[idx] = acc;
}

// ---------------------------------------------------------------------------
// Kernel 3: per-batch sequential part. 1 wave per batch, ZERO LDS.
//  fused phase 1+3: z and u=S*P recurrences via running per-lane accumulation
//  phase 2: S' column in 48 registers, fully unrolled, scalar wh loads
//  phase 4: Chat[b, lane*48+i] = s'_i[lane]  (contiguous per lane, float4)
// ---------------------------------------------------------------------------
__global__ __launch_bounds__(64) void k_seq(const float* __restrict__ W,
                                            const float* __restrict__ bvec,
                                            const float* __restrict__ P,
                                            float* __restrict__ Chat,
                                            float* __restrict__ mask_out) {
  const int b = blockIdx.x;
  const int lane = threadIdx.x;

  // per-lane wh row (lane j holds wh_j[k], k=0..46)
  float whr[47];
#pragma unroll
  for (int k = 0; k < 47; ++k)
    whr[k] = (lane < 48) ? W[lane * WROW + 256 + k] : 0.f;

  float Preg = (lane < 48) ? P[b * 48 + lane] : 0.f;
  float Pb = Preg + ((lane < 48) ? bvec[lane] : 0.f);

  // fused z- and u-recurrences:
  //   z_i = P_i + b_i + sum_{k<i} wh_i[k] a_k ,  a = relu(z), d = z>0
  //   u_i = P_i       + sum_{k<i} wh_i[k] o_k ,  o = d*u,  offs_i = a_i - o_i
  float accA = 0.f, accB = 0.f;
  float offs_lane = 0.f;
  int d_lane = 0;
#pragma unroll
  for (int i = 0; i < 48; ++i) {
    float z = Pb + accA;
    float u = Preg + accB;
    float a_i = fmaxf(z, 0.f);
    bool dpos = z > 0.f;
    float o_i = dpos ? u : 0.f;
    if (lane == i) {
      d_lane = dpos ? 1 : 0;
      offs_lane = a_i - o_i;
    }
    float ab = __shfl(a_i, i);
    float ob = __shfl(o_i, i);
    if (i < 47) {
      accA += whr[i] * ab;
      accB += whr[i] * ob;
    }
  }
  unsigned long long dmask = __ballot(d_lane);

  // phase 2: s[i] = s'_i[lane] = d_i * (sum_{k<i} wh_i[k] s[k] + (i==lane))
  float s[48];
  s[0] = ((dmask & 1ULL) && lane == 0) ? 1.f : 0.f;
#pragma unroll
  for (int i = 1; i < 48; ++i) {
    if ((dmask >> i) & 1ULL) {
      const float* wrow = W + i * WROW + 256;  // scalar (uniform) loads
      float t0 = (lane == i) ? 1.f : 0.f;
      float t1 = 0.f, t2 = 0.f, t3 = 0.f;
      int k = 0;
#pragma unroll
      for (; k + 3 < i; k += 4) {
        t0 += wrow[k + 0] * s[k + 0];
        t1 += wrow[k + 1] * s[k + 1];
        t2 += wrow[k + 2] * s[k + 2];
        t3 += wrow[k + 3] * s[k + 3];
      }
#pragma unroll
      for (; k < i; ++k) t0 += wrow[k] * s[k];
      s[i] = (t0 + t1) + (t2 + t3);
    } else {
      s[i] = 0.f;
    }
  }

  // phase 4: write Chat row (lane-contiguous layout) + offs + pad + masks
  float* base = Chat + (size_t)b * KPAD;
  if (lane < 48) {
    float* crow = base + (size_t)lane * 48;
#pragma unroll
    for (int m = 0; m < 12; ++m)
      *(float4*)&crow[4 * m] =
          make_float4(s[4 * m], s[4 * m + 1], s[4 * m + 2], s[4 * m + 3]);
    base[KC + lane] = offs_lane;
    mask_out[b * 48 + lane] = d_lane ? 1.f : 0.f;
  }
  if (lane < 52)
    *(float4*)&base[KHAT + lane * 4] = make_float4(0.f, 0.f, 0.f, 0.f);
}

// ---------------------------------------------------------------------------
// Tiled fp32 NT GEMM: out[m,n] = sum_k A[m,k]*B[n,k]  (+bias+relu if FINAL)
// BM=BN=64, BK=32, TM=TN=4, 256 threads. K-split via blockIdx.z -> partials.
// ---------------------------------------------------------------------------
template <bool FINAL>
__global__ __launch_bounds__(256) void k_gemm_nt(const float* __restrict__ A,
                                                 const float* __restrict__ Bm,
                                                 const float* __restrict__ bias,
                                                 float* __restrict__ Cdst,
                                                 int K, int CHUNK) {
  const int m0 = blockIdx.x * 64;
  const int n0 = blockIdx.y * 64;
  const int k0 = blockIdx.z * CHUNK;
  float* dst = Cdst + (size_t)blockIdx.z * (size_t)B_SZ * H_N;
  __shared__ float At[32][68];
  __shared__ float Bt[32][68];
  const int t = threadIdx.x;
  const int tn = t & 15, tm = t >> 4;
  float acc[4][4] = {};
  const int iters = CHUNK / 32;
  for (int it = 0; it < iters; ++it) {
    int kb = k0 + it * 32;
#pragma unroll
    for (int j = 0; j < 2; ++j) {
      int ef = t + j * 256;  // float4 index, 512 per tile
      int m = ef >> 3, c4 = ef & 7;
      float4 v = *(const float4*)&A[(size_t)(m0 + m) * K + kb + c4 * 4];
      At[c4 * 4 + 0][m] = v.x;
      At[c4 * 4 + 1][m] = v.y;
      At[c4 * 4 + 2][m] = v.z;
      At[c4 * 4 + 3][m] = v.w;
      float4 w = *(const float4*)&Bm[(size_t)(n0 + m) * K + kb + c4 * 4];
      Bt[c4 * 4 + 0][m] = w.x;
      Bt[c4 * 4 + 1][m] = w.y;
      Bt[c4 * 4 + 2][m] = w.z;
      Bt[c4 * 4 + 3][m] = w.w;
    }
    __syncthreads();
#pragma unroll
    for (int k = 0; k < 32; ++k) {
      float4 av = *(const float4*)&At[k][tm * 4];
      float4 bv = *(const float4*)&Bt[k][tn * 4];
      float aa[4] = {av.x, av.y, av.z, av.w};
      float bb[4] = {bv.x, bv.y, bv.z, bv.w};
#pragma unroll
      for (int ii = 0; ii < 4; ++ii)
#pragma unroll
        for (int jj = 0; jj < 4; ++jj) acc[ii][jj] += aa[ii] * bb[jj];
    }
    __syncthreads();
  }
#pragma unroll
  for (int ii = 0; ii < 4; ++ii) {
    int m = m0 + tm * 4 + ii;
    float* o = dst + (size_t)m * H_N + n0 + tn * 4;
    float4 v;
    if constexpr (FINAL) {
      v.x = fmaxf(acc[ii][0] + bias[n0 + tn * 4 + 0], 0.f);
      v.y = fmaxf(acc[ii][1] + bias[n0 + tn * 4 + 1], 0.f);
      v.z = fmaxf(acc[ii][2] + bias[n0 + tn * 4 + 2], 0.f);
      v.w = fmaxf(acc[ii][3] + bias[n0 + tn * 4 + 3], 0.f);
    } else {
      v = make_float4(acc[ii][0], acc[ii][1], acc[ii][2], acc[ii][3]);
    }
    *(float4*)o = v;
  }
}

// ---------------------------------------------------------------------------
// h0 = relu(part0+part1+part2+part3 + bb0), written IN PLACE into part0
// ---------------------------------------------------------------------------
__global__ __launch_bounds__(256) void k_reduce_relu(float* __restrict__ part,
                                                     const float* __restrict__ bias) {
  int idx = blockIdx.x * 256 + threadIdx.x;  // float4 index, 131072 total
  float4* p = (float4*)part;
  float4 a = p[idx];
  float4 b4 = p[idx + 131072];
  float4 c = p[idx + 262144];
  float4 d = p[idx + 393216];
  int n0 = (idx * 4) & 255;
  float4 bi = *(const float4*)&bias[n0];
  float4 r;
  r.x = fmaxf(a.x + b4.x + c.x + d.x + bi.x, 0.f);
  r.y = fmaxf(a.y + b4.y + c.y + d.y + bi.y, 0.f);
  r.z = fmaxf(a.z + b4.z + c.z + d.z + bi.z, 0.f);
  r.w = fmaxf(a.w + b4.w + c.w + d.w + bi.w, 0.f);
  p[idx] = r;
}

// ---------------------------------------------------------------------------
// out[b,o] = sum_k h1[b,k]*Wout[o,k] + bout[o]
// grid 32 x 64; Wout reads are wave-uniform -> scalar loads, no LDS.
// ---------------------------------------------------------------------------
__global__ __launch_bounds__(64) void k_out(const float* __restrict__ h1,
                                            const float* __restrict__ Wout,
                                            const float* __restrict__ bout,
                                            float* __restrict__ out) {
  int b = blockIdx.x * 64 + threadIdx.x;
  const float* hr = h1 + (size_t)b * H_N;
  float acc[10] = {};
#pragma unroll 4
  for (int k = 0; k < 256; ++k) {
    float h = hr[k];
#pragma unroll
    for (int o = 0; o < 10; ++o) acc[o] += Wout[o * 256 + k] * h;
  }
#pragma unroll
  for (int o = 0; o < 10; ++o) out[(size_t)b * O_N + o] = acc[o] + bout[o];
}

// ---------------------------------------------------------------------------
extern "C" void kernel_launch(void* const* d_in, const int* in_sizes, int n_in,
                              void* d_out, int out_size, void* d_ws,
                              size_t ws_size, hipStream_t stream) {
  (void)in_sizes; (void)n_in; (void)out_size; (void)ws_size;
  const float* x    = (const float*)d_in[0];
  const float* W    = (const float*)d_in[1];
  const float* bvec = (const float*)d_in[2];
  const float* Wb0  = (const float*)d_in[3];
  const float* bb0  = (const float*)d_in[4];
  const float* Wb1  = (const float*)d_in[5];
  const float* bb1  = (const float*)d_in[6];
  const float* Wout = (const float*)d_in[7];
  const float* bout = (const float*)d_in[8];

  float* out   = (float*)d_out;     // B*10
  float* masks = out + B_SZ * O_N;  // B*48

  float* ws   = (float*)d_ws;
  float* P    = ws;                                 // 2048*48
  float* Chat = P + B_SZ * L_N;                     // 2048*2560
  float* Ghat = Chat + (size_t)B_SZ * KPAD;         // 256*2560
  float* part = Ghat + (size_t)H_N * KPAD;          // 4 * 2048*256
  float* h0   = part;                               // alias region 0
  float* h1   = part + (size_t)B_SZ * H_N;          // alias region 1
  // total ~32.4 MB workspace

  k_ghat<<<dim3(48, 4), 256, 0, stream>>>(W, Wb0, Ghat);
  k_p<<<dim3(384), 256, 0, stream>>>(x, W, P);
  k_seq<<<dim3(2048), 64, 0, stream>>>(W, bvec, P, Chat, masks);
  // h0_pre = Chat @ Ghat^T, K=2560 split into 4 chunks of 640 (20 x BK=32)
  k_gemm_nt<false><<<dim3(32, 4, 4), 256, 0, stream>>>(Chat, Ghat, nullptr,
                                                       part, KPAD, 640);
  k_reduce_relu<<<dim3(512), 256, 0, stream>>>(part, bb0);
  // h1 = relu(h0 @ Wb1^T + bb1), K=256 single chunk
  k_gemm_nt<true><<<dim3(32, 4, 1), 256, 0, stream>>>(h0, Wb1, bb1, h1,
                                                      256, 256);
  k_out<<<dim3(32), 64, 0, stream>>>(h1, Wout, bout, out);
}

// Round 5
// 151.825 us; speedup vs baseline: 2.4756x; 1.2225x over previous
//
#include <hip/hip_runtime.h>

#define B_SZ 2048
#define D_IN 256
#define L_N 48
#define H_N 256
#define O_N 10
#define WROW 303      // D + L - 1
#define LEAF_N 12336  // L*(D+1)
#define KC 2304       // L*L
#define KHAT 2352     // KC + L (valid cols)
#define KPAD 2560     // padded K for BK=32 GEMM

// ---------------------------------------------------------------------------
// Kernel 1: Ghat[h, i*48+k] = sum_d W[k,d] * Wb0[h, i*257+d]   (i,k < 48)
//           Ghat[h, 2304+i] = Wb0[h, i*257+256]                (offset col)
//           Ghat[h, 2352..2560) = 0                            (pad, i==0 blk)
// Register-tiled NT GEMM per (i, h-tile): C[m=h 64][n=k 64pad], K=256.
// grid (48, 4), 256 threads, 4x4 acc/thread, float4 LDS reads.
// ---------------------------------------------------------------------------
__global__ __launch_bounds__(256) void k_ghat(const float* __restrict__ W,
                                              const float* __restrict__ Wb0,
                                              float* __restrict__ Ghat) {
  const int i  = blockIdx.x;       // layer
  const int h0 = blockIdx.y * 64;  // h tile
  __shared__ float At[32][68];     // [d][h]
  __shared__ float Bt[32][68];     // [d][k] (k>=48 zero)
  const int t = threadIdx.x;
  const int tn = t & 15, tm = t >> 4;
  float acc[4][4] = {};
  for (int it = 0; it < 8; ++it) {
    int kb = it * 32;
    // stage A: Wb0[h0+m, i*257+kb+c]  (row base i*257 unaligned -> dword)
    for (int e = t; e < 2048; e += 256) {
      int m = e >> 5, c = e & 31;
      At[c][m] = Wb0[(size_t)(h0 + m) * LEAF_N + i * 257 + kb + c];
    }
    // stage B: W[k, kb+c], zero-fill rows k>=48
    for (int e = t; e < 2048; e += 256) {
      int k = e >> 5, c = e & 31;
      Bt[c][k] = (k < 48) ? W[k * WROW + kb + c] : 0.f;
    }
    __syncthreads();
#pragma unroll
    for (int k = 0; k < 32; ++k) {
      float4 av = *(const float4*)&At[k][tm * 4];
      float4 bv = *(const float4*)&Bt[k][tn * 4];
      float aa[4] = {av.x, av.y, av.z, av.w};
      float bb[4] = {bv.x, bv.y, bv.z, bv.w};
#pragma unroll
      for (int ii = 0; ii < 4; ++ii)
#pragma unroll
        for (int jj = 0; jj < 4; ++jj) acc[ii][jj] += aa[ii] * bb[jj];
    }
    __syncthreads();
  }
  if (tn < 12) {  // valid k = tn*4..tn*4+3 < 48
#pragma unroll
    for (int ii = 0; ii < 4; ++ii)
      *(float4*)&Ghat[(size_t)(h0 + tm * 4 + ii) * KPAD + i * 48 + tn * 4] =
          make_float4(acc[ii][0], acc[ii][1], acc[ii][2], acc[ii][3]);
  }
  if (t < 64)  // offset column
    Ghat[(size_t)(h0 + t) * KPAD + KC + i] =
        Wb0[(size_t)(h0 + t) * LEAF_N + i * 257 + 256];
  if (i == 0) {  // pad-zero [2352,2560) for this h tile
    for (int e = t; e < 64 * 52; e += 256) {
      int r = e / 52, c = e - r * 52;
      *(float4*)&Ghat[(size_t)(h0 + r) * KPAD + KHAT + c * 4] =
          make_float4(0.f, 0.f, 0.f, 0.f);
    }
  }
}

// ---------------------------------------------------------------------------
// Kernel 2: P[b,i] = dot(x[b,:], W[i,0:256])
// ---------------------------------------------------------------------------
__global__ __launch_bounds__(256) void k_p(const float* __restrict__ x,
                                           const float* __restrict__ W,
                                           float* __restrict__ P) {
  int idx = blockIdx.x * 256 + threadIdx.x;  // 0..98303
  int b = idx / 48, i = idx - b * 48;
  const float* xr = x + (size_t)b * D_IN;
  const float* wr = W + (size_t)i * WROW;
  float acc = 0.f;
#pragma unroll 4
  for (int d = 0; d < 256; ++d) acc += xr[d] * wr[d];
  P[idx] = acc;
}

// ---------------------------------------------------------------------------
// Kernel 3: per-batch sequential part. 1 wave per batch, ZERO LDS.
//  fused phase 1+3: z and u=S*P recurrences via running per-lane accumulation
//  phase 2: S' column in 48 registers, fully unrolled, scalar wh loads
//  phase 4: Chat[b, i*48+lane] = s'_i[lane]  (lane-coalesced stores)
// ---------------------------------------------------------------------------
__global__ __launch_bounds__(64) void k_seq(const float* __restrict__ W,
                                            const float* __restrict__ bvec,
                                            const float* __restrict__ P,
                                            float* __restrict__ Chat,
                                            float* __restrict__ mask_out) {
  const int b = blockIdx.x;
  const int lane = threadIdx.x;

  // per-lane wh row (lane j holds wh_j[k], k=0..46)
  float whr[47];
#pragma unroll
  for (int k = 0; k < 47; ++k)
    whr[k] = (lane < 48) ? W[lane * WROW + 256 + k] : 0.f;

  float Preg = (lane < 48) ? P[b * 48 + lane] : 0.f;
  float Pb = Preg + ((lane < 48) ? bvec[lane] : 0.f);

  // fused z- and u-recurrences:
  //   z_i = P_i + b_i + sum_{k<i} wh_i[k] a_k ,  a = relu(z), d = z>0
  //   u_i = P_i       + sum_{k<i} wh_i[k] o_k ,  o = d*u,  offs_i = a_i - o_i
  float accA = 0.f, accB = 0.f;
  float offs_lane = 0.f;
  int d_lane = 0;
#pragma unroll
  for (int i = 0; i < 48; ++i) {
    float z = Pb + accA;
    float u = Preg + accB;
    float a_i = fmaxf(z, 0.f);
    bool dpos = z > 0.f;
    float o_i = dpos ? u : 0.f;
    if (lane == i) {
      d_lane = dpos ? 1 : 0;
      offs_lane = a_i - o_i;
    }
    float ab = __shfl(a_i, i);
    float ob = __shfl(o_i, i);
    if (i < 47) {
      accA += whr[i] * ab;
      accB += whr[i] * ob;
    }
  }
  unsigned long long dmask = __ballot(d_lane);

  // phase 2: s[i] = s'_i[lane] = d_i * (sum_{k<i} wh_i[k] s[k] + (i==lane))
  float s[48];
  s[0] = ((dmask & 1ULL) && lane == 0) ? 1.f : 0.f;
#pragma unroll
  for (int i = 1; i < 48; ++i) {
    if ((dmask >> i) & 1ULL) {
      const float* wrow = W + i * WROW + 256;  // scalar (uniform) loads
      float t0 = (lane == i) ? 1.f : 0.f;
      float t1 = 0.f, t2 = 0.f, t3 = 0.f;
      int k = 0;
#pragma unroll
      for (; k + 3 < i; k += 4) {
        t0 += wrow[k + 0] * s[k + 0];
        t1 += wrow[k + 1] * s[k + 1];
        t2 += wrow[k + 2] * s[k + 2];
        t3 += wrow[k + 3] * s[k + 3];
      }
#pragma unroll
      for (; k < i; ++k) t0 += wrow[k] * s[k];
      s[i] = (t0 + t1) + (t2 + t3);
    } else {
      s[i] = 0.f;
    }
  }

  // phase 4: write Chat row (i-major layout, lane-coalesced) + offs + pad
  float* base = Chat + (size_t)b * KPAD;
  if (lane < 48) {
#pragma unroll
    for (int i = 0; i < 48; ++i) base[i * 48 + lane] = s[i];
    base[KC + lane] = offs_lane;
    mask_out[b * 48 + lane] = d_lane ? 1.f : 0.f;
  }
  if (lane < 52)
    *(float4*)&base[KHAT + lane * 4] = make_float4(0.f, 0.f, 0.f, 0.f);
}

// ---------------------------------------------------------------------------
// Tiled fp32 NT GEMM: out[m,n] = sum_k A[m,k]*B[n,k]  (+bias+relu if FINAL)
// BM=BN=64, BK=32, TM=TN=4, 256 threads. K-split via blockIdx.z -> partials.
// ---------------------------------------------------------------------------
template <bool FINAL>
__global__ __launch_bounds__(256) void k_gemm_nt(const float* __restrict__ A,
                                                 const float* __restrict__ Bm,
                                                 const float* __restrict__ bias,
                                                 float* __restrict__ Cdst,
                                                 int K, int CHUNK) {
  const int m0 = blockIdx.x * 64;
  const int n0 = blockIdx.y * 64;
  const int k0 = blockIdx.z * CHUNK;
  float* dst = Cdst + (size_t)blockIdx.z * (size_t)B_SZ * H_N;
  __shared__ float At[32][68];
  __shared__ float Bt[32][68];
  const int t = threadIdx.x;
  const int tn = t & 15, tm = t >> 4;
  float acc[4][4] = {};
  const int iters = CHUNK / 32;
  for (int it = 0; it < iters; ++it) {
    int kb = k0 + it * 32;
#pragma unroll
    for (int j = 0; j < 2; ++j) {
      int ef = t + j * 256;  // float4 index, 512 per tile
      int m = ef >> 3, c4 = ef & 7;
      float4 v = *(const float4*)&A[(size_t)(m0 + m) * K + kb + c4 * 4];
      At[c4 * 4 + 0][m] = v.x;
      At[c4 * 4 + 1][m] = v.y;
      At[c4 * 4 + 2][m] = v.z;
      At[c4 * 4 + 3][m] = v.w;
      float4 w = *(const float4*)&Bm[(size_t)(n0 + m) * K + kb + c4 * 4];
      Bt[c4 * 4 + 0][m] = w.x;
      Bt[c4 * 4 + 1][m] = w.y;
      Bt[c4 * 4 + 2][m] = w.z;
      Bt[c4 * 4 + 3][m] = w.w;
    }
    __syncthreads();
#pragma unroll
    for (int k = 0; k < 32; ++k) {
      float4 av = *(const float4*)&At[k][tm * 4];
      float4 bv = *(const float4*)&Bt[k][tn * 4];
      float aa[4] = {av.x, av.y, av.z, av.w};
      float bb[4] = {bv.x, bv.y, bv.z, bv.w};
#pragma unroll
      for (int ii = 0; ii < 4; ++ii)
#pragma unroll
        for (int jj = 0; jj < 4; ++jj) acc[ii][jj] += aa[ii] * bb[jj];
    }
    __syncthreads();
  }
#pragma unroll
  for (int ii = 0; ii < 4; ++ii) {
    int m = m0 + tm * 4 + ii;
    float* o = dst + (size_t)m * H_N + n0 + tn * 4;
    float4 v;
    if constexpr (FINAL) {
      v.x = fmaxf(acc[ii][0] + bias[n0 + tn * 4 + 0], 0.f);
      v.y = fmaxf(acc[ii][1] + bias[n0 + tn * 4 + 1], 0.f);
      v.z = fmaxf(acc[ii][2] + bias[n0 + tn * 4 + 2], 0.f);
      v.w = fmaxf(acc[ii][3] + bias[n0 + tn * 4 + 3], 0.f);
    } else {
      v = make_float4(acc[ii][0], acc[ii][1], acc[ii][2], acc[ii][3]);
    }
    *(float4*)o = v;
  }
}

// ---------------------------------------------------------------------------
// h0 = relu(part0+part1+part2+part3 + bb0), written IN PLACE into part0
// ---------------------------------------------------------------------------
__global__ __launch_bounds__(256) void k_reduce_relu(float* __restrict__ part,
                                                     const float* __restrict__ bias) {
  int idx = blockIdx.x * 256 + threadIdx.x;  // float4 index, 131072 total
  float4* p = (float4*)part;
  float4 a = p[idx];
  float4 b4 = p[idx + 131072];
  float4 c = p[idx + 262144];
  float4 d = p[idx + 393216];
  int n0 = (idx * 4) & 255;
  float4 bi = *(const float4*)&bias[n0];
  float4 r;
  r.x = fmaxf(a.x + b4.x + c.x + d.x + bi.x, 0.f);
  r.y = fmaxf(a.y + b4.y + c.y + d.y + bi.y, 0.f);
  r.z = fmaxf(a.z + b4.z + c.z + d.z + bi.z, 0.f);
  r.w = fmaxf(a.w + b4.w + c.w + d.w + bi.w, 0.f);
  p[idx] = r;
}

// ---------------------------------------------------------------------------
// out[b,o] = sum_k h1[b,k]*Wout[o,k] + bout[o]
// grid 32 x 64; Wout reads are wave-uniform -> scalar loads, no LDS.
// ---------------------------------------------------------------------------
__global__ __launch_bounds__(64) void k_out(const float* __restrict__ h1,
                                            const float* __restrict__ Wout,
                                            const float* __restrict__ bout,
                                            float* __restrict__ out) {
  int b = blockIdx.x * 64 + threadIdx.x;
  const float* hr = h1 + (size_t)b * H_N;
  float acc[10] = {};
#pragma unroll 4
  for (int k = 0; k < 256; ++k) {
    float h = hr[k];
#pragma unroll
    for (int o = 0; o < 10; ++o) acc[o] += Wout[o * 256 + k] * h;
  }
#pragma unroll
  for (int o = 0; o < 10; ++o) out[(size_t)b * O_N + o] = acc[o] + bout[o];
}

// ---------------------------------------------------------------------------
extern "C" void kernel_launch(void* const* d_in, const int* in_sizes, int n_in,
                              void* d_out, int out_size, void* d_ws,
                              size_t ws_size, hipStream_t stream) {
  (void)in_sizes; (void)n_in; (void)out_size; (void)ws_size;
  const float* x    = (const float*)d_in[0];
  const float* W    = (const float*)d_in[1];
  const float* bvec = (const float*)d_in[2];
  const float* Wb0  = (const float*)d_in[3];
  const float* bb0  = (const float*)d_in[4];
  const float* Wb1  = (const float*)d_in[5];
  const float* bb1  = (const float*)d_in[6];
  const float* Wout = (const float*)d_in[7];
  const float* bout = (const float*)d_in[8];

  float* out   = (float*)d_out;     // B*10
  float* masks = out + B_SZ * O_N;  // B*48

  float* ws   = (float*)d_ws;
  float* P    = ws;                                 // 2048*48
  float* Chat = P + B_SZ * L_N;                     // 2048*2560
  float* Ghat = Chat + (size_t)B_SZ * KPAD;         // 256*2560
  float* part = Ghat + (size_t)H_N * KPAD;          // 4 * 2048*256
  float* h0   = part;                               // alias region 0
  float* h1   = part + (size_t)B_SZ * H_N;          // alias region 1
  // total ~32.4 MB workspace

  k_ghat<<<dim3(48, 4), 256, 0, stream>>>(W, Wb0, Ghat);
  k_p<<<dim3(384), 256, 0, stream>>>(x, W, P);
  k_seq<<<dim3(2048), 64, 0, stream>>>(W, bvec, P, Chat, masks);
  // h0_pre = Chat @ Ghat^T, K=2560 split into 4 chunks of 640 (20 x BK=32)
  k_gemm_nt<false><<<dim3(32, 4, 4), 256, 0, stream>>>(Chat, Ghat, nullptr,
                                                       part, KPAD, 640);
  k_reduce_relu<<<dim3(512), 256, 0, stream>>>(part, bb0);
  // h1 = relu(h0 @ Wb1^T + bb1), K=256 single chunk
  k_gemm_nt<true><<<dim3(32, 4, 1), 256, 0, stream>>>(h0, Wb1, bb1, h1,
                                                      256, 256);
  k_out<<<dim3(32), 64, 0, stream>>>(h1, Wout, bout, out);
}

// Round 6
// 110.552 us; speedup vs baseline: 3.3999x; 1.3733x over previous
//
#include <hip/hip_runtime.h>

#define B_SZ 2048
#define D_IN 256
#define L_N 48
#define H_N 256
#define O_N 10
#define WROW 303      // D + L - 1
#define LEAF_N 12336  // L*(D+1)
#define KC 2304       // L*L
#define KHAT 2352     // KC + L (valid cols)
#define KPAD 2560     // padded K (multiple of 64)

using short8 = __attribute__((ext_vector_type(8))) short;
using f32x4  = __attribute__((ext_vector_type(4))) float;

// split fp32 into bf16 hi (truncate) + bf16 lo (truncate of residual):
// v ~= hi + lo with |err| <= 2^-16 |v|
__device__ inline void bf16_split(float v, unsigned short& h, unsigned short& l) {
  unsigned bits = __float_as_uint(v);
  h = (unsigned short)(bits >> 16);
  float hf = __uint_as_float(bits & 0xFFFF0000u);
  float r = v - hf;
  l = (unsigned short)(__float_as_uint(r) >> 16);
}

// ---------------------------------------------------------------------------
// Kernel 1: Ghat[h, i*48+k] = sum_d W[k,d] * Wb0[h, i*257+d]  -> bf16 hi/lo
//           Ghat[h, 2304+i] = Wb0[h, i*257+256]; pad [2352,2560) = 0
// Register-tiled NT GEMM per (i, h-tile), fp32 internal.
// ---------------------------------------------------------------------------
__global__ __launch_bounds__(256) void k_ghat(const float* __restrict__ W,
                                              const float* __restrict__ Wb0,
                                              unsigned short* __restrict__ Gh,
                                              unsigned short* __restrict__ Gl) {
  const int i  = blockIdx.x;       // layer
  const int h0 = blockIdx.y * 64;  // h tile
  __shared__ float At[32][68];     // [d][h]
  __shared__ float Bt[32][68];     // [d][k] (k>=48 zero)
  const int t = threadIdx.x;
  const int tn = t & 15, tm = t >> 4;
  float acc[4][4] = {};
  for (int it = 0; it < 8; ++it) {
    int kb = it * 32;
    for (int e = t; e < 2048; e += 256) {
      int m = e >> 5, c = e & 31;
      At[c][m] = Wb0[(size_t)(h0 + m) * LEAF_N + i * 257 + kb + c];
    }
    for (int e = t; e < 2048; e += 256) {
      int k = e >> 5, c = e & 31;
      Bt[c][k] = (k < 48) ? W[k * WROW + kb + c] : 0.f;
    }
    __syncthreads();
#pragma unroll
    for (int k = 0; k < 32; ++k) {
      float4 av = *(const float4*)&At[k][tm * 4];
      float4 bv = *(const float4*)&Bt[k][tn * 4];
      float aa[4] = {av.x, av.y, av.z, av.w};
      float bb[4] = {bv.x, bv.y, bv.z, bv.w};
#pragma unroll
      for (int ii = 0; ii < 4; ++ii)
#pragma unroll
        for (int jj = 0; jj < 4; ++jj) acc[ii][jj] += aa[ii] * bb[jj];
    }
    __syncthreads();
  }
  if (tn < 12) {  // valid k = tn*4..tn*4+3 < 48
#pragma unroll
    for (int ii = 0; ii < 4; ++ii) {
      size_t o = (size_t)(h0 + tm * 4 + ii) * KPAD + i * 48 + tn * 4;
      ushort4 h4, l4;
      bf16_split(acc[ii][0], h4.x, l4.x);
      bf16_split(acc[ii][1], h4.y, l4.y);
      bf16_split(acc[ii][2], h4.z, l4.z);
      bf16_split(acc[ii][3], h4.w, l4.w);
      *(ushort4*)&Gh[o] = h4;
      *(ushort4*)&Gl[o] = l4;
    }
  }
  if (t < 64) {  // offset column
    unsigned short h, l;
    bf16_split(Wb0[(size_t)(h0 + t) * LEAF_N + i * 257 + 256], h, l);
    Gh[(size_t)(h0 + t) * KPAD + KC + i] = h;
    Gl[(size_t)(h0 + t) * KPAD + KC + i] = l;
  }
  if (i == 0) {  // pad-zero [2352,2560)
    for (int e = t; e < 64 * 52; e += 256) {
      int r = e / 52, c = e - r * 52;
      size_t o = (size_t)(h0 + r) * KPAD + KHAT + c * 4;
      *(ushort4*)&Gh[o] = make_ushort4(0, 0, 0, 0);
      *(ushort4*)&Gl[o] = make_ushort4(0, 0, 0, 0);
    }
  }
}

// ---------------------------------------------------------------------------
// Kernel 2: P[b,i] = dot(x[b,:], W[i,0:256])
// ---------------------------------------------------------------------------
__global__ __launch_bounds__(256) void k_p(const float* __restrict__ x,
                                           const float* __restrict__ W,
                                           float* __restrict__ P) {
  int idx = blockIdx.x * 256 + threadIdx.x;
  int b = idx / 48, i = idx - b * 48;
  const float* xr = x + (size_t)b * D_IN;
  const float* wr = W + (size_t)i * WROW;
  float acc = 0.f;
#pragma unroll 4
  for (int d = 0; d < 256; ++d) acc += xr[d] * wr[d];
  P[idx] = acc;
}

// ---------------------------------------------------------------------------
// Kernel 3: per-batch sequential part (1 wave/batch, no LDS), emits bf16 hi/lo
// ---------------------------------------------------------------------------
__global__ __launch_bounds__(64) void k_seq(const float* __restrict__ W,
                                            const float* __restrict__ bvec,
                                            const float* __restrict__ P,
                                            unsigned short* __restrict__ Ch,
                                            unsigned short* __restrict__ Cl,
                                            float* __restrict__ mask_out) {
  const int b = blockIdx.x;
  const int lane = threadIdx.x;

  float whr[47];
#pragma unroll
  for (int k = 0; k < 47; ++k)
    whr[k] = (lane < 48) ? W[lane * WROW + 256 + k] : 0.f;

  float Preg = (lane < 48) ? P[b * 48 + lane] : 0.f;
  float Pb = Preg + ((lane < 48) ? bvec[lane] : 0.f);

  float accA = 0.f, accB = 0.f;
  float offs_lane = 0.f;
  int d_lane = 0;
#pragma unroll
  for (int i = 0; i < 48; ++i) {
    float z = Pb + accA;
    float u = Preg + accB;
    float a_i = fmaxf(z, 0.f);
    bool dpos = z > 0.f;
    float o_i = dpos ? u : 0.f;
    if (lane == i) {
      d_lane = dpos ? 1 : 0;
      offs_lane = a_i - o_i;
    }
    float ab = __shfl(a_i, i);
    float ob = __shfl(o_i, i);
    if (i < 47) {
      accA += whr[i] * ab;
      accB += whr[i] * ob;
    }
  }
  unsigned long long dmask = __ballot(d_lane);

  float s[48];
  s[0] = ((dmask & 1ULL) && lane == 0) ? 1.f : 0.f;
#pragma unroll
  for (int i = 1; i < 48; ++i) {
    if ((dmask >> i) & 1ULL) {
      const float* wrow = W + i * WROW + 256;  // wave-uniform scalar loads
      float t0 = (lane == i) ? 1.f : 0.f;
      float t1 = 0.f, t2 = 0.f, t3 = 0.f;
      int k = 0;
#pragma unroll
      for (; k + 3 < i; k += 4) {
        t0 += wrow[k + 0] * s[k + 0];
        t1 += wrow[k + 1] * s[k + 1];
        t2 += wrow[k + 2] * s[k + 2];
        t3 += wrow[k + 3] * s[k + 3];
      }
#pragma unroll
      for (; k < i; ++k) t0 += wrow[k] * s[k];
      s[i] = (t0 + t1) + (t2 + t3);
    } else {
      s[i] = 0.f;
    }
  }

  size_t base = (size_t)b * KPAD;
  if (lane < 48) {
#pragma unroll
    for (int i = 0; i < 48; ++i) {
      unsigned short h, l;
      bf16_split(s[i], h, l);
      Ch[base + i * 48 + lane] = h;
      Cl[base + i * 48 + lane] = l;
    }
    unsigned short h, l;
    bf16_split(offs_lane, h, l);
    Ch[base + KC + lane] = h;
    Cl[base + KC + lane] = l;
    mask_out[b * 48 + lane] = d_lane ? 1.f : 0.f;
  }
  for (int e = lane; e < 208; e += 64) {  // pad [2352,2560)
    Ch[base + KHAT + e] = 0;
    Cl[base + KHAT + e] = 0;
  }
}

// ---------------------------------------------------------------------------
// Kernel 4: big GEMM via bf16 MFMA 3-term split.
// part[z][m,n] = sum_{k in chunk z} Chat[m,k]*Ghat[n,k]
// BM=BN=64, K-step 64, 4 waves (wave w: rows w*16..w*16+15, all 64 cols).
// LDS rows padded to 72 ushorts (144B): b128 reads at HW-minimum conflict.
// ---------------------------------------------------------------------------
__global__ __launch_bounds__(256) void k_gemm_bf16(
    const unsigned short* __restrict__ Ah, const unsigned short* __restrict__ Al,
    const unsigned short* __restrict__ Bh, const unsigned short* __restrict__ Bl,
    float* __restrict__ part) {
  const int m0 = blockIdx.x * 64;
  const int n0 = blockIdx.y * 64;
  const int k0 = blockIdx.z * 640;
  float* dst = part + (size_t)blockIdx.z * ((size_t)B_SZ * H_N);
  __shared__ unsigned short AhL[64 * 72], AlL[64 * 72];
  __shared__ unsigned short BhL[64 * 72], BlL[64 * 72];
  const int t = threadIdx.x;
  const int lane = t & 63;
  const int w = t >> 6;       // wave id -> m strip
  const int fr = lane & 15;   // fragment row/col
  const int fq = lane >> 4;   // k quarter
  f32x4 acc[4] = {};
  for (int it = 0; it < 10; ++it) {
    int kb = k0 + it * 64;
#pragma unroll
    for (int j = 0; j < 2; ++j) {
      int c = t + j * 256;
      int row = c >> 3, ko = (c & 7) * 8;
      size_t ga = (size_t)(m0 + row) * KPAD + kb + ko;
      size_t gb = (size_t)(n0 + row) * KPAD + kb + ko;
      *(short8*)&AhL[row * 72 + ko] = *(const short8*)&Ah[ga];
      *(short8*)&AlL[row * 72 + ko] = *(const short8*)&Al[ga];
      *(short8*)&BhL[row * 72 + ko] = *(const short8*)&Bh[gb];
      *(short8*)&BlL[row * 72 + ko] = *(const short8*)&Bl[gb];
    }
    __syncthreads();
#pragma unroll
    for (int ks = 0; ks < 2; ++ks) {
      int aoff = (w * 16 + fr) * 72 + fq * 8 + ks * 32;
      short8 ah = *(const short8*)&AhL[aoff];
      short8 al = *(const short8*)&AlL[aoff];
#pragma unroll
      for (int nt = 0; nt < 4; ++nt) {
        int boff = (nt * 16 + fr) * 72 + fq * 8 + ks * 32;
        short8 bh = *(const short8*)&BhL[boff];
        short8 bl = *(const short8*)&BlL[boff];
        acc[nt] = __builtin_amdgcn_mfma_f32_16x16x32_bf16(ah, bh, acc[nt], 0, 0, 0);
        acc[nt] = __builtin_amdgcn_mfma_f32_16x16x32_bf16(al, bh, acc[nt], 0, 0, 0);
        acc[nt] = __builtin_amdgcn_mfma_f32_16x16x32_bf16(ah, bl, acc[nt], 0, 0, 0);
      }
    }
    __syncthreads();
  }
  // C layout: col = lane&15, row = (lane>>4)*4 + reg  [m89-verified]
  int mrow = m0 + w * 16 + fq * 4;
#pragma unroll
  for (int nt = 0; nt < 4; ++nt) {
    int ncol = n0 + nt * 16 + fr;
#pragma unroll
    for (int r = 0; r < 4; ++r)
      dst[(size_t)(mrow + r) * H_N + ncol] = acc[nt][r];
  }
}

// ---------------------------------------------------------------------------
// h0 = relu(part0+part1+part2+part3 + bb0), in place into part0
// ---------------------------------------------------------------------------
__global__ __launch_bounds__(256) void k_reduce_relu(float* __restrict__ part,
                                                     const float* __restrict__ bias) {
  int idx = blockIdx.x * 256 + threadIdx.x;
  float4* p = (float4*)part;
  float4 a = p[idx];
  float4 b4 = p[idx + 131072];
  float4 c = p[idx + 262144];
  float4 d = p[idx + 393216];
  int n0 = (idx * 4) & 255;
  float4 bi = *(const float4*)&bias[n0];
  float4 r;
  r.x = fmaxf(a.x + b4.x + c.x + d.x + bi.x, 0.f);
  r.y = fmaxf(a.y + b4.y + c.y + d.y + bi.y, 0.f);
  r.z = fmaxf(a.z + b4.z + c.z + d.z + bi.z, 0.f);
  r.w = fmaxf(a.w + b4.w + c.w + d.w + bi.w, 0.f);
  p[idx] = r;
}

// ---------------------------------------------------------------------------
// Kernel 6: h1 = relu(h0 @ Wb1^T + bb1). BM=64, BN=32, grid (32,8)=256 blocks.
// ---------------------------------------------------------------------------
__global__ __launch_bounds__(256) void k_gemm2(const float* __restrict__ A,
                                               const float* __restrict__ Bm,
                                               const float* __restrict__ bias,
                                               float* __restrict__ h1) {
  const int m0 = blockIdx.x * 64;
  const int n0 = blockIdx.y * 32;
  __shared__ float At[32][68];
  __shared__ float Bt[32][36];
  const int t = threadIdx.x;
  const int tn = t & 7, tmq = t >> 3;  // 8 col-groups x 32 row-groups
  float acc[2][4] = {};
  for (int it = 0; it < 8; ++it) {
    int kb = it * 32;
#pragma unroll
    for (int j = 0; j < 2; ++j) {
      int c = t + j * 256;
      int m = c >> 3, c4 = c & 7;
      float4 v = *(const float4*)&A[(size_t)(m0 + m) * H_N + kb + c4 * 4];
      At[c4 * 4 + 0][m] = v.x;
      At[c4 * 4 + 1][m] = v.y;
      At[c4 * 4 + 2][m] = v.z;
      At[c4 * 4 + 3][m] = v.w;
    }
    {
      int m = t >> 3, c4 = t & 7;
      if (m < 32) {
        float4 v = *(const float4*)&Bm[(size_t)(n0 + m) * H_N + kb + c4 * 4];
        Bt[c4 * 4 + 0][m] = v.x;
        Bt[c4 * 4 + 1][m] = v.y;
        Bt[c4 * 4 + 2][m] = v.z;
        Bt[c4 * 4 + 3][m] = v.w;
      }
    }
    __syncthreads();
#pragma unroll
    for (int k = 0; k < 32; ++k) {
      float2 av = *(const float2*)&At[k][tmq * 2];
      float4 bv = *(const float4*)&Bt[k][tn * 4];
      acc[0][0] += av.x * bv.x; acc[0][1] += av.x * bv.y;
      acc[0][2] += av.x * bv.z; acc[0][3] += av.x * bv.w;
      acc[1][0] += av.y * bv.x; acc[1][1] += av.y * bv.y;
      acc[1][2] += av.y * bv.z; acc[1][3] += av.y * bv.w;
    }
    __syncthreads();
  }
#pragma unroll
  for (int ii = 0; ii < 2; ++ii) {
    int m = m0 + tmq * 2 + ii;
    float* o = h1 + (size_t)m * H_N + n0 + tn * 4;
    float4 v;
    v.x = fmaxf(acc[ii][0] + bias[n0 + tn * 4 + 0], 0.f);
    v.y = fmaxf(acc[ii][1] + bias[n0 + tn * 4 + 1], 0.f);
    v.z = fmaxf(acc[ii][2] + bias[n0 + tn * 4 + 2], 0.f);
    v.w = fmaxf(acc[ii][3] + bias[n0 + tn * 4 + 3], 0.f);
    *(float4*)o = v;
  }
}

// ---------------------------------------------------------------------------
// Kernel 7: out[b,:] = h1[b,:] @ Wout^T + bout. One wave per batch row.
// grid 512 x 256 (4 waves/block). Coalesced h1/Wout loads + butterfly reduce.
// ---------------------------------------------------------------------------
__global__ __launch_bounds__(256) void k_out(const float* __restrict__ h1,
                                             const float* __restrict__ Wout,
                                             const float* __restrict__ bout,
                                             float* __restrict__ out) {
  int w = threadIdx.x >> 6, lane = threadIdx.x & 63;
  int b = blockIdx.x * 4 + w;
  const float* hr = h1 + (size_t)b * H_N;
  float h[4];
#pragma unroll
  for (int j = 0; j < 4; ++j) h[j] = hr[lane + 64 * j];
  float acc[10];
#pragma unroll
  for (int o = 0; o < 10; ++o) {
    float s = 0.f;
#pragma unroll
    for (int j = 0; j < 4; ++j) s += h[j] * Wout[o * H_N + lane + 64 * j];
#pragma unroll
    for (int m = 32; m >= 1; m >>= 1) s += __shfl_xor(s, m);
    acc[o] = s;
  }
  if (lane == 0) {
#pragma unroll
    for (int o = 0; o < 10; ++o) out[(size_t)b * O_N + o] = acc[o] + bout[o];
  }
}

// ---------------------------------------------------------------------------
extern "C" void kernel_launch(void* const* d_in, const int* in_sizes, int n_in,
                              void* d_out, int out_size, void* d_ws,
                              size_t ws_size, hipStream_t stream) {
  (void)in_sizes; (void)n_in; (void)out_size; (void)ws_size;
  const float* x    = (const float*)d_in[0];
  const float* W    = (const float*)d_in[1];
  const float* bvec = (const float*)d_in[2];
  const float* Wb0  = (const float*)d_in[3];
  const float* bb0  = (const float*)d_in[4];
  const float* Wb1  = (const float*)d_in[5];
  const float* bb1  = (const float*)d_in[6];
  const float* Wout = (const float*)d_in[7];
  const float* bout = (const float*)d_in[8];

  float* out   = (float*)d_out;     // B*10
  float* masks = out + B_SZ * O_N;  // B*48

  char* wsb = (char*)d_ws;
  float* P = (float*)wsb;                                   // 393,216 B
  unsigned short* Ch = (unsigned short*)(wsb + 393216);     // B*KPAD us
  unsigned short* Cl = Ch + (size_t)B_SZ * KPAD;
  unsigned short* Gh = Cl + (size_t)B_SZ * KPAD;            // H*KPAD us
  unsigned short* Gl = Gh + (size_t)H_N * KPAD;
  float* part = (float*)(Gl + (size_t)H_N * KPAD);          // 4*B*H f32
  float* h0 = part;                                         // alias z=0
  float* h1 = part + (size_t)B_SZ * H_N;                    // alias z=1
  // total ~32.4 MB

  k_ghat<<<dim3(48, 4), 256, 0, stream>>>(W, Wb0, Gh, Gl);
  k_p<<<dim3(384), 256, 0, stream>>>(x, W, P);
  k_seq<<<dim3(2048), 64, 0, stream>>>(W, bvec, P, Ch, Cl, masks);
  k_gemm_bf16<<<dim3(32, 4, 4), 256, 0, stream>>>(Ch, Cl, Gh, Gl, part);
  k_reduce_relu<<<dim3(512), 256, 0, stream>>>(part, bb0);
  k_gemm2<<<dim3(32, 8), 256, 0, stream>>>(h0, Wb1, bb1, h1);
  k_out<<<dim3(512), 256, 0, stream>>>(h1, Wout, bout, out);
}

// Round 7
// 89.122 us; speedup vs baseline: 4.2174x; 1.2405x over previous
//
#include <hip/hip_runtime.h>

#define B_SZ 2048
#define D_IN 256
#define L_N 48
#define H_N 256
#define O_N 10
#define WROW 303      // D + L - 1
#define LEAF_N 12336  // L*(D+1)
#define KC 2304       // L*L
#define KHAT 2352     // KC + L (valid cols)
#define KPAD 2560     // padded K (multiple of 64)

using short8 = __attribute__((ext_vector_type(8))) short;
using f32x4  = __attribute__((ext_vector_type(4))) float;

// split fp32 into bf16 hi (truncate) + bf16 lo (truncate of residual):
// v ~= hi + lo with |err| <= 2^-16 |v|
__device__ inline void bf16_split(float v, unsigned short& h, unsigned short& l) {
  unsigned bits = __float_as_uint(v);
  h = (unsigned short)(bits >> 16);
  float hf = __uint_as_float(bits & 0xFFFF0000u);
  float r = v - hf;
  l = (unsigned short)(__float_as_uint(r) >> 16);
}

// ---------------------------------------------------------------------------
// Kernel 1a: partial Ghat GEMM.  Gp[z][h][i*48+k] = sum_{d in chunk z}
//   W[k,d] * Wb0[h, i*257+d].   grid (48 i, 4 h-tiles, 4 d-chunks), 256 thr.
// Staging: wave writes 4 rows x 16 cols -> LDS bank (4c+m)%32 = 2-way (free).
// ---------------------------------------------------------------------------
__global__ __launch_bounds__(256) void k_ghat(const float* __restrict__ W,
                                              const float* __restrict__ Wb0,
                                              float* __restrict__ Gp) {
  const int i  = blockIdx.x;        // layer
  const int h0 = blockIdx.y * 64;   // h tile
  const int dc = blockIdx.z * 64;   // d chunk
  __shared__ float At[64][68];      // [d][h]
  __shared__ float Bt[64][68];      // [d][k] (k>=48 zero)
  const int t = threadIdx.x;
  const int tn = t & 15, tm = t >> 4;
  const int sr = t & 3, sc = t >> 2;  // staging: 4 rows x 64 cols per pass
#pragma unroll
  for (int j = 0; j < 16; ++j) {
    int r = sr + j * 4;
    At[sc][r] = Wb0[(size_t)(h0 + r) * LEAF_N + i * 257 + dc + sc];
    Bt[sc][r] = (r < 48) ? W[r * WROW + dc + sc] : 0.f;
  }
  __syncthreads();
  float acc[4][4] = {};
#pragma unroll 8
  for (int d = 0; d < 64; ++d) {
    float4 av = *(const float4*)&At[d][tm * 4];
    float4 bv = *(const float4*)&Bt[d][tn * 4];
    float aa[4] = {av.x, av.y, av.z, av.w};
    float bb[4] = {bv.x, bv.y, bv.z, bv.w};
#pragma unroll
    for (int ii = 0; ii < 4; ++ii)
#pragma unroll
      for (int jj = 0; jj < 4; ++jj) acc[ii][jj] += aa[ii] * bb[jj];
  }
  if (tn < 12) {
    float* gz = Gp + (size_t)blockIdx.z * (H_N * KC);
#pragma unroll
    for (int ii = 0; ii < 4; ++ii)
      *(float4*)&gz[(size_t)(h0 + tm * 4 + ii) * KC + i * 48 + tn * 4] =
          make_float4(acc[ii][0], acc[ii][1], acc[ii][2], acc[ii][3]);
  }
}

// ---------------------------------------------------------------------------
// Kernel 1b: combine partials -> bf16 hi/lo Ghat; add offset col + pad.
// grid 256 (one block per h), 256 threads.
// ---------------------------------------------------------------------------
__global__ __launch_bounds__(256) void k_gcomb(const float* __restrict__ Gp,
                                               const float* __restrict__ Wb0,
                                               unsigned short* __restrict__ Gh,
                                               unsigned short* __restrict__ Gl) {
  const int h = blockIdx.x;
  const int t = threadIdx.x;
  for (int e = t; e < KC / 4; e += 256) {  // 576 float4 groups
    float4 s0 = *(const float4*)&Gp[(size_t)h * KC + e * 4];
    float4 s1 = *(const float4*)&Gp[(size_t)(H_N + h) * KC + e * 4];
    float4 s2 = *(const float4*)&Gp[(size_t)(2 * H_N + h) * KC + e * 4];
    float4 s3 = *(const float4*)&Gp[(size_t)(3 * H_N + h) * KC + e * 4];
    float v[4] = {s0.x + s1.x + s2.x + s3.x, s0.y + s1.y + s2.y + s3.y,
                  s0.z + s1.z + s2.z + s3.z, s0.w + s1.w + s2.w + s3.w};
    ushort4 h4, l4;
    bf16_split(v[0], h4.x, l4.x);
    bf16_split(v[1], h4.y, l4.y);
    bf16_split(v[2], h4.z, l4.z);
    bf16_split(v[3], h4.w, l4.w);
    *(ushort4*)&Gh[(size_t)h * KPAD + e * 4] = h4;
    *(ushort4*)&Gl[(size_t)h * KPAD + e * 4] = l4;
  }
  if (t < 48) {  // offset column
    unsigned short hh, ll;
    bf16_split(Wb0[(size_t)h * LEAF_N + t * 257 + 256], hh, ll);
    Gh[(size_t)h * KPAD + KC + t] = hh;
    Gl[(size_t)h * KPAD + KC + t] = ll;
  }
  for (int e = KHAT + t; e < KPAD; e += 256) {  // pad
    Gh[(size_t)h * KPAD + e] = 0;
    Gl[(size_t)h * KPAD + e] = 0;
  }
}

// ---------------------------------------------------------------------------
// Kernel 2: P[b,i] = dot(x[b,:], W[i,0:256])
// ---------------------------------------------------------------------------
__global__ __launch_bounds__(256) void k_p(const float* __restrict__ x,
                                           const float* __restrict__ W,
                                           float* __restrict__ P) {
  int idx = blockIdx.x * 256 + threadIdx.x;
  int b = idx / 48, i = idx - b * 48;
  const float* xr = x + (size_t)b * D_IN;
  const float* wr = W + (size_t)i * WROW;
  float acc = 0.f;
#pragma unroll 4
  for (int d = 0; d < 256; ++d) acc += xr[d] * wr[d];
  P[idx] = acc;
}

// ---------------------------------------------------------------------------
// Kernel 3: per-batch sequential part (1 wave/batch, no LDS), emits bf16 hi/lo
// ---------------------------------------------------------------------------
__global__ __launch_bounds__(64) void k_seq(const float* __restrict__ W,
                                            const float* __restrict__ bvec,
                                            const float* __restrict__ P,
                                            unsigned short* __restrict__ Ch,
                                            unsigned short* __restrict__ Cl,
                                            float* __restrict__ mask_out) {
  const int b = blockIdx.x;
  const int lane = threadIdx.x;

  float whr[47];
#pragma unroll
  for (int k = 0; k < 47; ++k)
    whr[k] = (lane < 48) ? W[lane * WROW + 256 + k] : 0.f;

  float Preg = (lane < 48) ? P[b * 48 + lane] : 0.f;
  float Pb = Preg + ((lane < 48) ? bvec[lane] : 0.f);

  float accA = 0.f, accB = 0.f;
  float offs_lane = 0.f;
  int d_lane = 0;
#pragma unroll
  for (int i = 0; i < 48; ++i) {
    float z = Pb + accA;
    float u = Preg + accB;
    float a_i = fmaxf(z, 0.f);
    bool dpos = z > 0.f;
    float o_i = dpos ? u : 0.f;
    if (lane == i) {
      d_lane = dpos ? 1 : 0;
      offs_lane = a_i - o_i;
    }
    float ab = __shfl(a_i, i);
    float ob = __shfl(o_i, i);
    if (i < 47) {
      accA += whr[i] * ab;
      accB += whr[i] * ob;
    }
  }
  unsigned long long dmask = __ballot(d_lane);

  float s[48];
  s[0] = ((dmask & 1ULL) && lane == 0) ? 1.f : 0.f;
#pragma unroll
  for (int i = 1; i < 48; ++i) {
    if ((dmask >> i) & 1ULL) {
      const float* wrow = W + i * WROW + 256;  // wave-uniform scalar loads
      float t0 = (lane == i) ? 1.f : 0.f;
      float t1 = 0.f, t2 = 0.f, t3 = 0.f;
      int k = 0;
#pragma unroll
      for (; k + 3 < i; k += 4) {
        t0 += wrow[k + 0] * s[k + 0];
        t1 += wrow[k + 1] * s[k + 1];
        t2 += wrow[k + 2] * s[k + 2];
        t3 += wrow[k + 3] * s[k + 3];
      }
#pragma unroll
      for (; k < i; ++k) t0 += wrow[k] * s[k];
      s[i] = (t0 + t1) + (t2 + t3);
    } else {
      s[i] = 0.f;
    }
  }

  size_t base = (size_t)b * KPAD;
  if (lane < 48) {
#pragma unroll
    for (int i = 0; i < 48; ++i) {
      unsigned short h, l;
      bf16_split(s[i], h, l);
      Ch[base + i * 48 + lane] = h;
      Cl[base + i * 48 + lane] = l;
    }
    unsigned short h, l;
    bf16_split(offs_lane, h, l);
    Ch[base + KC + lane] = h;
    Cl[base + KC + lane] = l;
    mask_out[b * 48 + lane] = d_lane ? 1.f : 0.f;
  }
  for (int e = lane; e < 208; e += 64) {  // pad [2352,2560)
    Ch[base + KHAT + e] = 0;
    Cl[base + KHAT + e] = 0;
  }
}

// ---------------------------------------------------------------------------
// Kernel 4: big GEMM via bf16 MFMA 3-term split.
// part[z][m,n] = sum_{k in chunk z} Chat[m,k]*Ghat[n,k]
// BM=BN=64, K-step 64, 4 waves. LDS row stride 88 shorts (176B, 16B-aligned):
// fragment-read bank base (12*fr+4*fq)%32 -> 2-way (free); writes 2-way.
// ---------------------------------------------------------------------------
#define LDSP 88
__global__ __launch_bounds__(256) void k_gemm_bf16(
    const unsigned short* __restrict__ Ah, const unsigned short* __restrict__ Al,
    const unsigned short* __restrict__ Bh, const unsigned short* __restrict__ Bl,
    float* __restrict__ part) {
  const int m0 = blockIdx.x * 64;
  const int n0 = blockIdx.y * 64;
  const int k0 = blockIdx.z * 640;
  float* dst = part + (size_t)blockIdx.z * ((size_t)B_SZ * H_N);
  __shared__ unsigned short AhL[64 * LDSP], AlL[64 * LDSP];
  __shared__ unsigned short BhL[64 * LDSP], BlL[64 * LDSP];
  const int t = threadIdx.x;
  const int lane = t & 63;
  const int w = t >> 6;       // wave id -> m strip
  const int fr = lane & 15;   // fragment row/col
  const int fq = lane >> 4;   // k quarter
  f32x4 acc[4] = {};
  for (int it = 0; it < 10; ++it) {
    int kb = k0 + it * 64;
#pragma unroll
    for (int j = 0; j < 2; ++j) {
      int c = t + j * 256;
      int row = c >> 3, ko = (c & 7) * 8;
      size_t ga = (size_t)(m0 + row) * KPAD + kb + ko;
      size_t gb = (size_t)(n0 + row) * KPAD + kb + ko;
      *(short8*)&AhL[row * LDSP + ko] = *(const short8*)&Ah[ga];
      *(short8*)&AlL[row * LDSP + ko] = *(const short8*)&Al[ga];
      *(short8*)&BhL[row * LDSP + ko] = *(const short8*)&Bh[gb];
      *(short8*)&BlL[row * LDSP + ko] = *(const short8*)&Bl[gb];
    }
    __syncthreads();
#pragma unroll
    for (int ks = 0; ks < 2; ++ks) {
      int aoff = (w * 16 + fr) * LDSP + fq * 8 + ks * 32;
      short8 ah = *(const short8*)&AhL[aoff];
      short8 al = *(const short8*)&AlL[aoff];
#pragma unroll
      for (int nt = 0; nt < 4; ++nt) {
        int boff = (nt * 16 + fr) * LDSP + fq * 8 + ks * 32;
        short8 bh = *(const short8*)&BhL[boff];
        short8 bl = *(const short8*)&BlL[boff];
        acc[nt] = __builtin_amdgcn_mfma_f32_16x16x32_bf16(ah, bh, acc[nt], 0, 0, 0);
        acc[nt] = __builtin_amdgcn_mfma_f32_16x16x32_bf16(al, bh, acc[nt], 0, 0, 0);
        acc[nt] = __builtin_amdgcn_mfma_f32_16x16x32_bf16(ah, bl, acc[nt], 0, 0, 0);
      }
    }
    __syncthreads();
  }
  // C layout: col = lane&15, row = (lane>>4)*4 + reg  [m89-verified]
  int mrow = m0 + w * 16 + fq * 4;
#pragma unroll
  for (int nt = 0; nt < 4; ++nt) {
    int ncol = n0 + nt * 16 + fr;
#pragma unroll
    for (int r = 0; r < 4; ++r)
      dst[(size_t)(mrow + r) * H_N + ncol] = acc[nt][r];
  }
}

// ---------------------------------------------------------------------------
// h0 = relu(part0+part1+part2+part3 + bb0), in place into part0
// ---------------------------------------------------------------------------
__global__ __launch_bounds__(256) void k_reduce_relu(float* __restrict__ part,
                                                     const float* __restrict__ bias) {
  int idx = blockIdx.x * 256 + threadIdx.x;
  float4* p = (float4*)part;
  float4 a = p[idx];
  float4 b4 = p[idx + 131072];
  float4 c = p[idx + 262144];
  float4 d = p[idx + 393216];
  int n0 = (idx * 4) & 255;
  float4 bi = *(const float4*)&bias[n0];
  float4 r;
  r.x = fmaxf(a.x + b4.x + c.x + d.x + bi.x, 0.f);
  r.y = fmaxf(a.y + b4.y + c.y + d.y + bi.y, 0.f);
  r.z = fmaxf(a.z + b4.z + c.z + d.z + bi.z, 0.f);
  r.w = fmaxf(a.w + b4.w + c.w + d.w + bi.w, 0.f);
  p[idx] = r;
}

// ---------------------------------------------------------------------------
// Kernel 6: h1 = relu(h0 @ Wb1^T + bb1). BM=64, BN=32, grid (32,8)=256 blocks.
// ---------------------------------------------------------------------------
__global__ __launch_bounds__(256) void k_gemm2(const float* __restrict__ A,
                                               const float* __restrict__ Bm,
                                               const float* __restrict__ bias,
                                               float* __restrict__ h1) {
  const int m0 = blockIdx.x * 64;
  const int n0 = blockIdx.y * 32;
  __shared__ float At[32][68];
  __shared__ float Bt[32][36];
  const int t = threadIdx.x;
  const int tn = t & 7, tmq = t >> 3;  // 8 col-groups x 32 row-groups
  float acc[2][4] = {};
  for (int it = 0; it < 8; ++it) {
    int kb = it * 32;
#pragma unroll
    for (int j = 0; j < 2; ++j) {
      int c = t + j * 256;
      int m = c >> 3, c4 = c & 7;
      float4 v = *(const float4*)&A[(size_t)(m0 + m) * H_N + kb + c4 * 4];
      At[c4 * 4 + 0][m] = v.x;
      At[c4 * 4 + 1][m] = v.y;
      At[c4 * 4 + 2][m] = v.z;
      At[c4 * 4 + 3][m] = v.w;
    }
    {
      int m = t >> 3, c4 = t & 7;
      if (m < 32) {
        float4 v = *(const float4*)&Bm[(size_t)(n0 + m) * H_N + kb + c4 * 4];
        Bt[c4 * 4 + 0][m] = v.x;
        Bt[c4 * 4 + 1][m] = v.y;
        Bt[c4 * 4 + 2][m] = v.z;
        Bt[c4 * 4 + 3][m] = v.w;
      }
    }
    __syncthreads();
#pragma unroll
    for (int k = 0; k < 32; ++k) {
      float2 av = *(const float2*)&At[k][tmq * 2];
      float4 bv = *(const float4*)&Bt[k][tn * 4];
      acc[0][0] += av.x * bv.x; acc[0][1] += av.x * bv.y;
      acc[0][2] += av.x * bv.z; acc[0][3] += av.x * bv.w;
      acc[1][0] += av.y * bv.x; acc[1][1] += av.y * bv.y;
      acc[1][2] += av.y * bv.z; acc[1][3] += av.y * bv.w;
    }
    __syncthreads();
  }
#pragma unroll
  for (int ii = 0; ii < 2; ++ii) {
    int m = m0 + tmq * 2 + ii;
    float* o = h1 + (size_t)m * H_N + n0 + tn * 4;
    float4 v;
    v.x = fmaxf(acc[ii][0] + bias[n0 + tn * 4 + 0], 0.f);
    v.y = fmaxf(acc[ii][1] + bias[n0 + tn * 4 + 1], 0.f);
    v.z = fmaxf(acc[ii][2] + bias[n0 + tn * 4 + 2], 0.f);
    v.w = fmaxf(acc[ii][3] + bias[n0 + tn * 4 + 3], 0.f);
    *(float4*)o = v;
  }
}

// ---------------------------------------------------------------------------
// Kernel 7: out[b,:] = h1[b,:] @ Wout^T + bout. One wave per batch row.
// ---------------------------------------------------------------------------
__global__ __launch_bounds__(256) void k_out(const float* __restrict__ h1,
                                             const float* __restrict__ Wout,
                                             const float* __restrict__ bout,
                                             float* __restrict__ out) {
  int w = threadIdx.x >> 6, lane = threadIdx.x & 63;
  int b = blockIdx.x * 4 + w;
  const float* hr = h1 + (size_t)b * H_N;
  float h[4];
#pragma unroll
  for (int j = 0; j < 4; ++j) h[j] = hr[lane + 64 * j];
  float acc[10];
#pragma unroll
  for (int o = 0; o < 10; ++o) {
    float s = 0.f;
#pragma unroll
    for (int j = 0; j < 4; ++j) s += h[j] * Wout[o * H_N + lane + 64 * j];
#pragma unroll
    for (int m = 32; m >= 1; m >>= 1) s += __shfl_xor(s, m);
    acc[o] = s;
  }
  if (lane == 0) {
#pragma unroll
    for (int o = 0; o < 10; ++o) out[(size_t)b * O_N + o] = acc[o] + bout[o];
  }
}

// ---------------------------------------------------------------------------
extern "C" void kernel_launch(void* const* d_in, const int* in_sizes, int n_in,
                              void* d_out, int out_size, void* d_ws,
                              size_t ws_size, hipStream_t stream) {
  (void)in_sizes; (void)n_in; (void)out_size; (void)ws_size;
  const float* x    = (const float*)d_in[0];
  const float* W    = (const float*)d_in[1];
  const float* bvec = (const float*)d_in[2];
  const float* Wb0  = (const float*)d_in[3];
  const float* bb0  = (const float*)d_in[4];
  const float* Wb1  = (const float*)d_in[5];
  const float* bb1  = (const float*)d_in[6];
  const float* Wout = (const float*)d_in[7];
  const float* bout = (const float*)d_in[8];

  float* out   = (float*)d_out;     // B*10
  float* masks = out + B_SZ * O_N;  // B*48

  char* wsb = (char*)d_ws;
  float* P = (float*)wsb;                                   // 393,216 B
  unsigned short* Ch = (unsigned short*)(wsb + 393216);     // B*KPAD us
  unsigned short* Cl = Ch + (size_t)B_SZ * KPAD;
  unsigned short* Gh = Cl + (size_t)B_SZ * KPAD;            // H*KPAD us
  unsigned short* Gl = Gh + (size_t)H_N * KPAD;
  float* part = (float*)(Gl + (size_t)H_N * KPAD);          // 4*B*H f32
  float* h0 = part;                                         // alias z=0
  float* h1 = part + (size_t)B_SZ * H_N;                    // alias z=1
  float* Gp = part + 4 * (size_t)B_SZ * H_N;                // 4*H*KC f32
  // total ~42 MB

  k_ghat<<<dim3(48, 4, 4), 256, 0, stream>>>(W, Wb0, Gp);
  k_gcomb<<<dim3(256), 256, 0, stream>>>(Gp, Wb0, Gh, Gl);
  k_p<<<dim3(384), 256, 0, stream>>>(x, W, P);
  k_seq<<<dim3(2048), 64, 0, stream>>>(W, bvec, P, Ch, Cl, masks);
  k_gemm_bf16<<<dim3(32, 4, 4), 256, 0, stream>>>(Ch, Cl, Gh, Gl, part);
  k_reduce_relu<<<dim3(512), 256, 0, stream>>>(part, bb0);
  k_gemm2<<<dim3(32, 8), 256, 0, stream>>>(h0, Wb1, bb1, h1);
  k_out<<<dim3(512), 256, 0, stream>>>(h1, Wout, bout, out);
}

// Round 8
// 84.053 us; speedup vs baseline: 4.4717x; 1.0603x over previous
//
#include <hip/hip_runtime.h>

#define B_SZ 2048
#define D_IN 256
#define L_N 48
#define H_N 256
#define O_N 10
#define WROW 303      // D + L - 1
#define LEAF_N 12336  // L*(D+1)
#define KC 2304       // L*L
#define KHAT 2352     // KC + L (valid cols)
#define KPAD 2560     // padded K (multiple of 64)

using short8 = __attribute__((ext_vector_type(8))) short;
using f32x4  = __attribute__((ext_vector_type(4))) float;

// split fp32 into bf16 hi (truncate) + bf16 lo (truncate of residual)
__device__ inline void bf16_split(float v, unsigned short& h, unsigned short& l) {
  unsigned bits = __float_as_uint(v);
  h = (unsigned short)(bits >> 16);
  float hf = __uint_as_float(bits & 0xFFFF0000u);
  float r = v - hf;
  l = (unsigned short)(__float_as_uint(r) >> 16);
}

// ---------------------------------------------------------------------------
// Kernel 1: merged phase-1. blocks [0,768): Ghat partial GEMM
//   Gp[z][h][i*48+k] = sum_{d in chunk z} W[k,d]*Wb0[h,i*257+d]
// blocks [768,1152): P[b,i] = dot(x[b,:], W[i,0:256])
// ---------------------------------------------------------------------------
__global__ __launch_bounds__(256) void k_phase1(const float* __restrict__ W,
                                                const float* __restrict__ Wb0,
                                                const float* __restrict__ x,
                                                float* __restrict__ Gp,
                                                float* __restrict__ P) {
  const int bid = blockIdx.x;
  const int t = threadIdx.x;
  if (bid < 768) {
    const int i  = bid % 48;              // layer
    const int rest = bid / 48;            // 0..15
    const int h0 = (rest & 3) * 64;       // h tile
    const int dc = (rest >> 2) * 64;      // d chunk
    __shared__ float At[64][68];          // [d][h]
    __shared__ float Bt[64][68];          // [d][k] (k>=48 zero)
    const int tn = t & 15, tm = t >> 4;
    const int sr = t & 3, sc = t >> 2;    // staging: 4 rows x 64 cols
#pragma unroll
    for (int j = 0; j < 16; ++j) {
      int r = sr + j * 4;
      At[sc][r] = Wb0[(size_t)(h0 + r) * LEAF_N + i * 257 + dc + sc];
      Bt[sc][r] = (r < 48) ? W[r * WROW + dc + sc] : 0.f;
    }
    __syncthreads();
    float acc[4][4] = {};
#pragma unroll 8
    for (int d = 0; d < 64; ++d) {
      float4 av = *(const float4*)&At[d][tm * 4];
      float4 bv = *(const float4*)&Bt[d][tn * 4];
      float aa[4] = {av.x, av.y, av.z, av.w};
      float bb[4] = {bv.x, bv.y, bv.z, bv.w};
#pragma unroll
      for (int ii = 0; ii < 4; ++ii)
#pragma unroll
        for (int jj = 0; jj < 4; ++jj) acc[ii][jj] += aa[ii] * bb[jj];
    }
    if (tn < 12) {
      float* gz = Gp + (size_t)(rest >> 2) * (H_N * KC);
#pragma unroll
      for (int ii = 0; ii < 4; ++ii)
        *(float4*)&gz[(size_t)(h0 + tm * 4 + ii) * KC + i * 48 + tn * 4] =
            make_float4(acc[ii][0], acc[ii][1], acc[ii][2], acc[ii][3]);
    }
  } else {
    int idx = (bid - 768) * 256 + t;  // 0..98303
    int b = idx / 48, i = idx - b * 48;
    const float* xr = x + (size_t)b * D_IN;
    const float* wr = W + (size_t)i * WROW;
    float acc = 0.f;
#pragma unroll 4
    for (int d = 0; d < 256; ++d) acc += xr[d] * wr[d];
    P[idx] = acc;
  }
}

// ---------------------------------------------------------------------------
// Kernel 1b: combine partials -> bf16 hi/lo Ghat; offset col + pad.
// ---------------------------------------------------------------------------
__global__ __launch_bounds__(256) void k_gcomb(const float* __restrict__ Gp,
                                               const float* __restrict__ Wb0,
                                               unsigned short* __restrict__ Gh,
                                               unsigned short* __restrict__ Gl) {
  const int h = blockIdx.x;
  const int t = threadIdx.x;
  for (int e = t; e < KC / 4; e += 256) {
    float4 s0 = *(const float4*)&Gp[(size_t)h * KC + e * 4];
    float4 s1 = *(const float4*)&Gp[(size_t)(H_N + h) * KC + e * 4];
    float4 s2 = *(const float4*)&Gp[(size_t)(2 * H_N + h) * KC + e * 4];
    float4 s3 = *(const float4*)&Gp[(size_t)(3 * H_N + h) * KC + e * 4];
    float v[4] = {s0.x + s1.x + s2.x + s3.x, s0.y + s1.y + s2.y + s3.y,
                  s0.z + s1.z + s2.z + s3.z, s0.w + s1.w + s2.w + s3.w};
    ushort4 h4, l4;
    bf16_split(v[0], h4.x, l4.x);
    bf16_split(v[1], h4.y, l4.y);
    bf16_split(v[2], h4.z, l4.z);
    bf16_split(v[3], h4.w, l4.w);
    *(ushort4*)&Gh[(size_t)h * KPAD + e * 4] = h4;
    *(ushort4*)&Gl[(size_t)h * KPAD + e * 4] = l4;
  }
  if (t < 48) {
    unsigned short hh, ll;
    bf16_split(Wb0[(size_t)h * LEAF_N + t * 257 + 256], hh, ll);
    Gh[(size_t)h * KPAD + KC + t] = hh;
    Gl[(size_t)h * KPAD + KC + t] = ll;
  }
  for (int e = KHAT + t; e < KPAD; e += 256) {
    Gh[(size_t)h * KPAD + e] = 0;
    Gl[(size_t)h * KPAD + e] = 0;
  }
}

// ---------------------------------------------------------------------------
// Kernel 3: per-batch sequential part (1 wave/batch, no LDS), bf16 hi/lo out
// ---------------------------------------------------------------------------
__global__ __launch_bounds__(64) void k_seq(const float* __restrict__ W,
                                            const float* __restrict__ bvec,
                                            const float* __restrict__ P,
                                            unsigned short* __restrict__ Ch,
                                            unsigned short* __restrict__ Cl,
                                            float* __restrict__ mask_out) {
  const int b = blockIdx.x;
  const int lane = threadIdx.x;

  float whr[47];
#pragma unroll
  for (int k = 0; k < 47; ++k)
    whr[k] = (lane < 48) ? W[lane * WROW + 256 + k] : 0.f;

  float Preg = (lane < 48) ? P[b * 48 + lane] : 0.f;
  float Pb = Preg + ((lane < 48) ? bvec[lane] : 0.f);

  float accA = 0.f, accB = 0.f;
  float offs_lane = 0.f;
  int d_lane = 0;
#pragma unroll
  for (int i = 0; i < 48; ++i) {
    float z = Pb + accA;
    float u = Preg + accB;
    float a_i = fmaxf(z, 0.f);
    bool dpos = z > 0.f;
    float o_i = dpos ? u : 0.f;
    if (lane == i) {
      d_lane = dpos ? 1 : 0;
      offs_lane = a_i - o_i;
    }
    float ab = __shfl(a_i, i);
    float ob = __shfl(o_i, i);
    if (i < 47) {
      accA += whr[i] * ab;
      accB += whr[i] * ob;
    }
  }
  unsigned long long dmask = __ballot(d_lane);

  float s[48];
  s[0] = ((dmask & 1ULL) && lane == 0) ? 1.f : 0.f;
#pragma unroll
  for (int i = 1; i < 48; ++i) {
    if ((dmask >> i) & 1ULL) {
      const float* wrow = W + i * WROW + 256;  // wave-uniform scalar loads
      float t0 = (lane == i) ? 1.f : 0.f;
      float t1 = 0.f, t2 = 0.f, t3 = 0.f;
      int k = 0;
#pragma unroll
      for (; k + 3 < i; k += 4) {
        t0 += wrow[k + 0] * s[k + 0];
        t1 += wrow[k + 1] * s[k + 1];
        t2 += wrow[k + 2] * s[k + 2];
        t3 += wrow[k + 3] * s[k + 3];
      }
#pragma unroll
      for (; k < i; ++k) t0 += wrow[k] * s[k];
      s[i] = (t0 + t1) + (t2 + t3);
    } else {
      s[i] = 0.f;
    }
  }

  size_t base = (size_t)b * KPAD;
  if (lane < 48) {
#pragma unroll
    for (int i = 0; i < 48; ++i) {
      unsigned short h, l;
      bf16_split(s[i], h, l);
      Ch[base + i * 48 + lane] = h;
      Cl[base + i * 48 + lane] = l;
    }
    unsigned short h, l;
    bf16_split(offs_lane, h, l);
    Ch[base + KC + lane] = h;
    Cl[base + KC + lane] = l;
    mask_out[b * 48 + lane] = d_lane ? 1.f : 0.f;
  }
  for (int e = lane; e < 208; e += 64) {
    Ch[base + KHAT + e] = 0;
    Cl[base + KHAT + e] = 0;
  }
}

// ---------------------------------------------------------------------------
// Kernel 4: big GEMM via bf16 MFMA 3-term split, XCD-chunk-swizzled.
// flat id (x fastest = HW order) -> id=(flat%8)*64+flat/8 so each XCD owns
// 64 consecutive ids covering 4 m-panels (x slowest within chunk):
// A panels fetched once device-wide; B (2.6 MB) L2-resident per XCD.
// ---------------------------------------------------------------------------
#define LDSP 88
__global__ __launch_bounds__(256) void k_gemm_bf16(
    const unsigned short* __restrict__ Ah, const unsigned short* __restrict__ Al,
    const unsigned short* __restrict__ Bh, const unsigned short* __restrict__ Bl,
    float* __restrict__ part) {
  int flat = blockIdx.x + 32 * blockIdx.y + 128 * blockIdx.z;  // 0..511
  int id = (flat & 7) * 64 + (flat >> 3);                      // XCD chunks
  const int bz = id & 3, by = (id >> 2) & 3, bx = id >> 4;
  const int m0 = bx * 64;
  const int n0 = by * 64;
  const int k0 = bz * 640;
  float* dst = part + (size_t)bz * ((size_t)B_SZ * H_N);
  __shared__ unsigned short AhL[64 * LDSP], AlL[64 * LDSP];
  __shared__ unsigned short BhL[64 * LDSP], BlL[64 * LDSP];
  const int t = threadIdx.x;
  const int lane = t & 63;
  const int w = t >> 6;
  const int fr = lane & 15;
  const int fq = lane >> 4;
  f32x4 acc[4] = {};
  for (int it = 0; it < 10; ++it) {
    int kb = k0 + it * 64;
#pragma unroll
    for (int j = 0; j < 2; ++j) {
      int c = t + j * 256;
      int row = c >> 3, ko = (c & 7) * 8;
      size_t ga = (size_t)(m0 + row) * KPAD + kb + ko;
      size_t gb = (size_t)(n0 + row) * KPAD + kb + ko;
      *(short8*)&AhL[row * LDSP + ko] = *(const short8*)&Ah[ga];
      *(short8*)&AlL[row * LDSP + ko] = *(const short8*)&Al[ga];
      *(short8*)&BhL[row * LDSP + ko] = *(const short8*)&Bh[gb];
      *(short8*)&BlL[row * LDSP + ko] = *(const short8*)&Bl[gb];
    }
    __syncthreads();
#pragma unroll
    for (int ks = 0; ks < 2; ++ks) {
      int aoff = (w * 16 + fr) * LDSP + fq * 8 + ks * 32;
      short8 ah = *(const short8*)&AhL[aoff];
      short8 al = *(const short8*)&AlL[aoff];
#pragma unroll
      for (int nt = 0; nt < 4; ++nt) {
        int boff = (nt * 16 + fr) * LDSP + fq * 8 + ks * 32;
        short8 bh = *(const short8*)&BhL[boff];
        short8 bl = *(const short8*)&BlL[boff];
        acc[nt] = __builtin_amdgcn_mfma_f32_16x16x32_bf16(ah, bh, acc[nt], 0, 0, 0);
        acc[nt] = __builtin_amdgcn_mfma_f32_16x16x32_bf16(al, bh, acc[nt], 0, 0, 0);
        acc[nt] = __builtin_amdgcn_mfma_f32_16x16x32_bf16(ah, bl, acc[nt], 0, 0, 0);
      }
    }
    __syncthreads();
  }
  // C layout: col = lane&15, row = (lane>>4)*4 + reg  [m89-verified]
  int mrow = m0 + w * 16 + fq * 4;
#pragma unroll
  for (int nt = 0; nt < 4; ++nt) {
    int ncol = n0 + nt * 16 + fr;
#pragma unroll
    for (int r = 0; r < 4; ++r)
      dst[(size_t)(mrow + r) * H_N + ncol] = acc[nt][r];
  }
}

// ---------------------------------------------------------------------------
// Kernel 6: h1 = relu( relu(sum_z part_z + bb0) @ Wb1^T + bb1 )  -- the h0
// reduce+bias+relu is FUSED into A-staging. XCD-chunk-swizzled.
// BM=64, BN=32, grid (32,8)=256 blocks.
// ---------------------------------------------------------------------------
__global__ __launch_bounds__(256) void k_gemm2f(const float* __restrict__ part,
                                                const float* __restrict__ bb0,
                                                const float* __restrict__ Bm,
                                                const float* __restrict__ bias,
                                                float* __restrict__ h1) {
  int flat = blockIdx.x + 32 * blockIdx.y;      // 0..255
  int id = (flat & 7) * 32 + (flat >> 3);       // XCD chunks, x slowest
  const int m0 = (id >> 3) * 64;
  const int n0 = (id & 7) * 32;
  const size_t BH = (size_t)B_SZ * H_N;
  __shared__ float At[32][68];
  __shared__ float Bt[32][36];
  const int t = threadIdx.x;
  const int tn = t & 7, tmq = t >> 3;
  float acc[2][4] = {};
  for (int it = 0; it < 8; ++it) {
    int kb = it * 32;
#pragma unroll
    for (int j = 0; j < 2; ++j) {
      int c = t + j * 256;
      int m = c >> 3, c4 = c & 7;
      size_t base = (size_t)(m0 + m) * H_N + kb + c4 * 4;
      float4 v0 = *(const float4*)&part[base];
      float4 v1 = *(const float4*)&part[base + BH];
      float4 v2 = *(const float4*)&part[base + 2 * BH];
      float4 v3 = *(const float4*)&part[base + 3 * BH];
      float4 bi = *(const float4*)&bb0[kb + c4 * 4];
      At[c4 * 4 + 0][m] = fmaxf(v0.x + v1.x + v2.x + v3.x + bi.x, 0.f);
      At[c4 * 4 + 1][m] = fmaxf(v0.y + v1.y + v2.y + v3.y + bi.y, 0.f);
      At[c4 * 4 + 2][m] = fmaxf(v0.z + v1.z + v2.z + v3.z + bi.z, 0.f);
      At[c4 * 4 + 3][m] = fmaxf(v0.w + v1.w + v2.w + v3.w + bi.w, 0.f);
    }
    {
      int m = t >> 3, c4 = t & 7;
      if (m < 32) {
        float4 v = *(const float4*)&Bm[(size_t)(n0 + m) * H_N + kb + c4 * 4];
        Bt[c4 * 4 + 0][m] = v.x;
        Bt[c4 * 4 + 1][m] = v.y;
        Bt[c4 * 4 + 2][m] = v.z;
        Bt[c4 * 4 + 3][m] = v.w;
      }
    }
    __syncthreads();
#pragma unroll
    for (int k = 0; k < 32; ++k) {
      float2 av = *(const float2*)&At[k][tmq * 2];
      float4 bv = *(const float4*)&Bt[k][tn * 4];
      acc[0][0] += av.x * bv.x; acc[0][1] += av.x * bv.y;
      acc[0][2] += av.x * bv.z; acc[0][3] += av.x * bv.w;
      acc[1][0] += av.y * bv.x; acc[1][1] += av.y * bv.y;
      acc[1][2] += av.y * bv.z; acc[1][3] += av.y * bv.w;
    }
    __syncthreads();
  }
#pragma unroll
  for (int ii = 0; ii < 2; ++ii) {
    int m = m0 + tmq * 2 + ii;
    float* o = h1 + (size_t)m * H_N + n0 + tn * 4;
    float4 v;
    v.x = fmaxf(acc[ii][0] + bias[n0 + tn * 4 + 0], 0.f);
    v.y = fmaxf(acc[ii][1] + bias[n0 + tn * 4 + 1], 0.f);
    v.z = fmaxf(acc[ii][2] + bias[n0 + tn * 4 + 2], 0.f);
    v.w = fmaxf(acc[ii][3] + bias[n0 + tn * 4 + 3], 0.f);
    *(float4*)o = v;
  }
}

// ---------------------------------------------------------------------------
// Kernel 7: out[b,:] = h1[b,:] @ Wout^T + bout. One wave per batch row.
// ---------------------------------------------------------------------------
__global__ __launch_bounds__(256) void k_out(const float* __restrict__ h1,
                                             const float* __restrict__ Wout,
                                             const float* __restrict__ bout,
                                             float* __restrict__ out) {
  int w = threadIdx.x >> 6, lane = threadIdx.x & 63;
  int b = blockIdx.x * 4 + w;
  const float* hr = h1 + (size_t)b * H_N;
  float h[4];
#pragma unroll
  for (int j = 0; j < 4; ++j) h[j] = hr[lane + 64 * j];
  float acc[10];
#pragma unroll
  for (int o = 0; o < 10; ++o) {
    float s = 0.f;
#pragma unroll
    for (int j = 0; j < 4; ++j) s += h[j] * Wout[o * H_N + lane + 64 * j];
#pragma unroll
    for (int m = 32; m >= 1; m >>= 1) s += __shfl_xor(s, m);
    acc[o] = s;
  }
  if (lane == 0) {
#pragma unroll
    for (int o = 0; o < 10; ++o) out[(size_t)b * O_N + o] = acc[o] + bout[o];
  }
}

// ---------------------------------------------------------------------------
extern "C" void kernel_launch(void* const* d_in, const int* in_sizes, int n_in,
                              void* d_out, int out_size, void* d_ws,
                              size_t ws_size, hipStream_t stream) {
  (void)in_sizes; (void)n_in; (void)out_size; (void)ws_size;
  const float* x    = (const float*)d_in[0];
  const float* W    = (const float*)d_in[1];
  const float* bvec = (const float*)d_in[2];
  const float* Wb0  = (const float*)d_in[3];
  const float* bb0  = (const float*)d_in[4];
  const float* Wb1  = (const float*)d_in[5];
  const float* bb1  = (const float*)d_in[6];
  const float* Wout = (const float*)d_in[7];
  const float* bout = (const float*)d_in[8];

  float* out   = (float*)d_out;     // B*10
  float* masks = out + B_SZ * O_N;  // B*48

  char* wsb = (char*)d_ws;
  float* P = (float*)wsb;                                   // 393,216 B
  unsigned short* Ch = (unsigned short*)(wsb + 393216);     // B*KPAD us
  unsigned short* Cl = Ch + (size_t)B_SZ * KPAD;
  unsigned short* Gh = Cl + (size_t)B_SZ * KPAD;            // H*KPAD us
  unsigned short* Gl = Gh + (size_t)H_N * KPAD;
  float* part = (float*)(Gl + (size_t)H_N * KPAD);          // 4*B*H f32
  float* Gp = part + 4 * (size_t)B_SZ * H_N;                // 4*H*KC f32
  float* h1 = Gp;                                           // alias (Gp dead)
  // total ~42 MB

  k_phase1<<<dim3(1152), 256, 0, stream>>>(W, Wb0, x, Gp, P);
  k_gcomb<<<dim3(256), 256, 0, stream>>>(Gp, Wb0, Gh, Gl);
  k_seq<<<dim3(2048), 64, 0, stream>>>(W, bvec, P, Ch, Cl, masks);
  k_gemm_bf16<<<dim3(32, 4, 4), 256, 0, stream>>>(Ch, Cl, Gh, Gl, part);
  k_gemm2f<<<dim3(32, 8), 256, 0, stream>>>(part, bb0, Wb1, bb1, h1);
  k_out<<<dim3(512), 256, 0, stream>>>(h1, Wout, bout, out);
}